// Round 1
// baseline (331.042 us; speedup 1.0000x reference)
//
#include <hip/hip_runtime.h>
#include <hip/hip_bf16.h>
#include <math.h>

typedef __attribute__((ext_vector_type(8))) short short8;
typedef __attribute__((ext_vector_type(4))) float f32x4;
typedef __attribute__((ext_vector_type(4))) unsigned int u32x4;

#define NB   128   // batch
#define TT   64    // timesteps (T-1)
#define DD   512   // feature dim
#define HH   128   // hidden dim
#define WVD  128   // wordvec dim
#define VV   10000 // vocab
#define VP   10048 // vocab padded to multiple of 64
#define NROW (NB*TT)

__device__ __forceinline__ unsigned short f2bf(float x) {
  union { float f; unsigned int u; } v; v.f = x;
  unsigned int r = v.u + 0x7fffu + ((v.u >> 16) & 1u);
  return (unsigned short)(r >> 16);
}

// K0: h0 = features @ W_proj + b_proj ; also zero the output scalar
__global__ __launch_bounds__(128) void k_h0(const float* __restrict__ features,
    const float* __restrict__ Wp, const float* __restrict__ bp,
    float* __restrict__ h0, float* __restrict__ out) {
  __shared__ float fl[DD];
  int n = blockIdx.x, j = threadIdx.x;
  if (n == 0 && j == 0) out[0] = 0.f;
  for (int k = j; k < DD; k += HH) fl[k] = features[n*DD + k];
  __syncthreads();
  float s = bp[j];
  #pragma unroll 4
  for (int k = 0; k < DD; ++k) s += fl[k] * Wp[k*HH + j];  // coalesced over j
  h0[n*HH + j] = s;
}

// K1: Wih_t[k][j] = W_ih[j][k]  (so xb kernel reads coalesced over j)
__global__ __launch_bounds__(256) void k_twih(const float* __restrict__ Wih,
                                              float* __restrict__ Wt) {
  int o = blockIdx.x*256 + threadIdx.x;  // o = k*128 + j
  int k = o >> 7, j = o & 127;
  Wt[o] = Wih[j*WVD + k];
}

// K2: Wvt[v][k] = bf16(W_vocab[k][v]), zero-padded rows v in [VV, VP)
__global__ __launch_bounds__(256) void k_twv(const float* __restrict__ Wv,
                                             unsigned short* __restrict__ Wvt) {
  int o = blockIdx.x*256 + threadIdx.x;  // o = v*128 + k
  int v = o >> 7, k = o & 127;
  float val = (v < VV) ? Wv[(size_t)k*VV + v] : 0.f;
  Wvt[o] = f2bf(val);
}

// K3: xb[r][j] = b_ih[j]+b_hh[j] + sum_k embed[cap_in[r]][k] * W_ih[j][k]
// 4 rows per thread to reuse each W element 4x.
__global__ __launch_bounds__(256) void k_xb(const int* __restrict__ captions,
    const float* __restrict__ embed, const float* __restrict__ Wt,
    const float* __restrict__ bih, const float* __restrict__ bhh,
    float* __restrict__ xb) {
  int g = blockIdx.x*256 + threadIdx.x;   // 262144 threads
  int j = g & 127;
  int rq = g >> 7;                         // 0..2047
  int r0 = rq, r1 = rq + 2048, r2 = rq + 4096, r3 = rq + 6144;
  const float* x0 = embed + (size_t)captions[(r0>>6)*65 + (r0&63)] * WVD;
  const float* x1 = embed + (size_t)captions[(r1>>6)*65 + (r1&63)] * WVD;
  const float* x2 = embed + (size_t)captions[(r2>>6)*65 + (r2&63)] * WVD;
  const float* x3 = embed + (size_t)captions[(r3>>6)*65 + (r3&63)] * WVD;
  float b = bih[j] + bhh[j];
  float a0 = b, a1 = b, a2 = b, a3 = b;
  #pragma unroll 4
  for (int k = 0; k < WVD; ++k) {
    float w = Wt[k*HH + j];                // coalesced over j, L1/L2 hot
    a0 += x0[k]*w; a1 += x1[k]*w; a2 += x2[k]*w; a3 += x3[k]*w;
  }
  xb[(size_t)r0*HH + j] = a0;
  xb[(size_t)r1*HH + j] = a1;
  xb[(size_t)r2*HH + j] = a2;
  xb[(size_t)r3*HH + j] = a3;
}

// K4: the sequential RNN. One block per sample n (independent over batch).
// W_hh staged in LDS padded to 129 floats/row -> conflict-free reads.
// 256 threads: thread (j, half) computes half the K-dot, LDS tree combine.
__global__ __launch_bounds__(256) void k_rnn(const float* __restrict__ h0,
    const float* __restrict__ xb, const float* __restrict__ Whh,
    float* __restrict__ hs) {
  __shared__ float Wh[HH*129];
  __shared__ float hcur[HH];
  __shared__ float part[256];
  int n = blockIdx.x, tid = threadIdx.x;
  for (int i = tid; i < HH*HH; i += 256) {
    int r = i >> 7, c = i & 127;
    Wh[r*129 + c] = Whh[i];
  }
  if (tid < HH) hcur[tid] = h0[n*HH + tid];
  __syncthreads();
  int j = tid & 127, half = tid >> 7, kb = half*64;
  const float* wr = &Wh[j*129 + kb];
  for (int t = 0; t < TT; ++t) {
    float s0 = 0.f, s1 = 0.f;
    const float* hr = &hcur[kb];
    #pragma unroll 8
    for (int k = 0; k < 64; k += 2) { s0 += hr[k]*wr[k]; s1 += hr[k+1]*wr[k+1]; }
    part[tid] = s0 + s1;
    __syncthreads();
    if (tid < HH) {
      float v = part[tid] + part[tid+128] + xb[(size_t)(n*TT + t)*HH + tid];
      float h = tanhf(v);
      hcur[tid] = h;
      hs[(size_t)(n*TT + t)*HH + tid] = h;
    }
    __syncthreads();
  }
}

// K5: fused scores + log-softmax + target NLL + masked mean.
// 256 blocks x 32 rows. 4 waves: wave = (rowhalf rh, colpair cp).
// A (h rows, bf16) held in registers; B (W_vocab cols) staged in
// XOR-swizzled LDS; mfma 16x16x32 bf16; epilogue: running sum-exp +
// target-score capture per lane, then shfl + LDS reduce + atomicAdd.
__global__ __launch_bounds__(256) void k_loss(const float* __restrict__ hs,
    const unsigned short* __restrict__ wvt, const float* __restrict__ bv,
    const int* __restrict__ captions, float* __restrict__ out) {
  __shared__ unsigned short bt[64*128];     // 16 KB, swizzled
  __shared__ float red[4][4][4][2];
  int tid = threadIdx.x;
  int w = tid >> 6, l = tid & 63;
  int l4 = l >> 4, lc = l & 15;
  int rowbase = blockIdx.x * 32;
  int rh = w >> 1, cp = w & 1;
  int arow = rowbase + rh*16 + lc;          // A-fragment row (l&15)

  short8 af[4];
  #pragma unroll
  for (int ks = 0; ks < 4; ++ks) {
    const float* p = hs + (size_t)arow*HH + ks*32 + l4*8;
    f32x4 x0 = *(const f32x4*)p;
    f32x4 x1 = *(const f32x4*)(p + 4);
    short8 t;
    t[0]=(short)f2bf(x0[0]); t[1]=(short)f2bf(x0[1]);
    t[2]=(short)f2bf(x0[2]); t[3]=(short)f2bf(x0[3]);
    t[4]=(short)f2bf(x1[0]); t[5]=(short)f2bf(x1[1]);
    t[6]=(short)f2bf(x1[2]); t[7]=(short)f2bf(x1[3]);
    af[ks] = t;
  }
  int tgt[4];
  #pragma unroll
  for (int jj = 0; jj < 4; ++jj) {
    int r = rowbase + rh*16 + l4*4 + jj;    // C/D row = (lane>>4)*4 + reg
    int n = r >> 6, t = r & 63;
    tgt[jj] = captions[n*65 + t + 1];
  }
  float se[4] = {0,0,0,0}, ts[4] = {0,0,0,0};

  for (int vs = 0; vs < VP/64; ++vs) {
    int vbase = vs*64;
    __syncthreads();
    #pragma unroll
    for (int i = 0; i < 4; ++i) {
      int chunk = i*256 + tid;              // 1024 x 16B
      int c = chunk >> 4, k8 = chunk & 15;
      u32x4 gv = *(const u32x4*)(wvt + (size_t)(vbase + c)*HH + k8*8);
      int byte = c*256 + ((k8*16) ^ ((c & 7) << 4));
      *(u32x4*)((char*)bt + byte) = gv;
    }
    __syncthreads();
    #pragma unroll
    for (int st2 = 0; st2 < 2; ++st2) {
      int st = cp*2 + st2;
      int c = st*16 + lc;                   // B col within 64-stage
      f32x4 acc = {0.f, 0.f, 0.f, 0.f};
      #pragma unroll
      for (int ks = 0; ks < 4; ++ks) {
        int byte = c*256 + (((ks*4 + l4)*16) ^ ((c & 7) << 4));
        short8 bf = *(const short8*)((const char*)bt + byte);
        acc = __builtin_amdgcn_mfma_f32_16x16x32_bf16(af[ks], bf, acc, 0, 0, 0);
      }
      int col = vbase + st*16 + lc;
      bool valid = col < VV;
      float bvv = valid ? bv[col] : 0.f;
      #pragma unroll
      for (int jj = 0; jj < 4; ++jj) {
        float s = acc[jj] + bvv;
        if (valid) {
          se[jj] += __expf(s);
          if (col == tgt[jj]) ts[jj] = s;
        }
      }
    }
  }
  #pragma unroll
  for (int jj = 0; jj < 4; ++jj) {
    #pragma unroll
    for (int m = 1; m < 16; m <<= 1) {
      se[jj] += __shfl_xor(se[jj], m);
      ts[jj] += __shfl_xor(ts[jj], m);
    }
  }
  if (lc == 0) {
    #pragma unroll
    for (int jj = 0; jj < 4; ++jj) {
      red[w][l4][jj][0] = se[jj];
      red[w][l4][jj][1] = ts[jj];
    }
  }
  __syncthreads();
  if (tid < 32) {
    int r = tid, rh2 = r >> 4, rr = r & 15, g = rr >> 2, jj = rr & 3;
    float sesum = red[rh2*2][g][jj][0] + red[rh2*2+1][g][jj][0];
    float tssum = red[rh2*2][g][jj][1] + red[rh2*2+1][g][jj][1];
    int row = rowbase + r;
    int n = row >> 6, t = row & 63;
    int tg = captions[n*65 + t + 1];
    if (tg != 0) {
      float nll = logf(sesum) - tssum;
      atomicAdd(out, nll * (1.0f/128.0f));
    }
  }
}

extern "C" void kernel_launch(void* const* d_in, const int* in_sizes, int n_in,
                              void* d_out, int out_size, void* d_ws, size_t ws_size,
                              hipStream_t stream) {
  const float* features = (const float*)d_in[0];
  const int*   captions = (const int*)d_in[1];
  const float* W_proj   = (const float*)d_in[2];
  const float* b_proj   = (const float*)d_in[3];
  const float* embed    = (const float*)d_in[4];
  const float* W_ih     = (const float*)d_in[5];
  const float* W_hh     = (const float*)d_in[6];
  const float* b_ih     = (const float*)d_in[7];
  const float* b_hh     = (const float*)d_in[8];
  const float* W_vocab  = (const float*)d_in[9];
  const float* b_vocab  = (const float*)d_in[10];
  float* out = (float*)d_out;
  char* ws = (char*)d_ws;

  float* h0    = (float*)(ws);                          // 64 KB
  float* xb    = (float*)(ws + 65536);                  // 4 MB
  float* hs    = (float*)(ws + 65536 + 4194304);        // 4 MB
  float* wih_t = (float*)(ws + 65536 + 8388608);        // 64 KB
  unsigned short* wvt = (unsigned short*)(ws + 131072 + 8388608); // 2.57 MB

  hipLaunchKernelGGL(k_h0,  dim3(NB), dim3(HH), 0, stream, features, W_proj, b_proj, h0, out);
  hipLaunchKernelGGL(k_twih, dim3((HH*WVD)/256), dim3(256), 0, stream, W_ih, wih_t);
  hipLaunchKernelGGL(k_twv,  dim3((VP*HH)/256), dim3(256), 0, stream, W_vocab, wvt);
  hipLaunchKernelGGL(k_xb,   dim3((NROW*HH/4)/256), dim3(256), 0, stream, captions, embed, wih_t, b_ih, b_hh, xb);
  hipLaunchKernelGGL(k_rnn,  dim3(NB), dim3(256), 0, stream, h0, xb, W_hh, hs);
  hipLaunchKernelGGL(k_loss, dim3(NROW/32), dim3(256), 0, stream, hs, wvt, b_vocab, captions, out);
}

// Round 2
// 330.601 us; speedup vs baseline: 1.0013x; 1.0013x over previous
//
#include <hip/hip_runtime.h>
#include <hip/hip_bf16.h>
#include <math.h>

typedef __attribute__((ext_vector_type(8))) short short8;
typedef __attribute__((ext_vector_type(4))) float f32x4;
typedef __attribute__((ext_vector_type(4))) unsigned int u32x4;

#define NB   128   // batch
#define TT   64    // timesteps (T-1)
#define DD   512   // feature dim
#define HH   128   // hidden dim
#define WVD  128   // wordvec dim
#define VV   10000 // vocab
#define VP   10048 // vocab padded to multiple of 64
#define NROW (NB*TT)

__device__ __forceinline__ unsigned short f2bf(float x) {
  union { float f; unsigned int u; } v; v.f = x;
  unsigned int r = v.u + 0x7fffu + ((v.u >> 16) & 1u);
  return (unsigned short)(r >> 16);
}

// K0: h0 = features @ W_proj + b_proj ; also zero the output scalar
__global__ __launch_bounds__(128) void k_h0(const float* __restrict__ features,
    const float* __restrict__ Wp, const float* __restrict__ bp,
    float* __restrict__ h0, float* __restrict__ out) {
  __shared__ float fl[DD];
  int n = blockIdx.x, j = threadIdx.x;
  if (n == 0 && j == 0) out[0] = 0.f;
  for (int k = j; k < DD; k += HH) fl[k] = features[n*DD + k];
  __syncthreads();
  float s = bp[j];
  #pragma unroll 4
  for (int k = 0; k < DD; ++k) s += fl[k] * Wp[k*HH + j];  // coalesced over j
  h0[n*HH + j] = s;
}

// K1: Wih_t[k][j] = W_ih[j][k]  (so xb kernel reads coalesced over j)
__global__ __launch_bounds__(256) void k_twih(const float* __restrict__ Wih,
                                              float* __restrict__ Wt) {
  int o = blockIdx.x*256 + threadIdx.x;  // o = k*128 + j
  int k = o >> 7, j = o & 127;
  Wt[o] = Wih[j*WVD + k];
}

// K2: Wvt[v][k] = bf16(W_vocab[k][v]), zero-padded rows v in [VV, VP)
__global__ __launch_bounds__(256) void k_twv(const float* __restrict__ Wv,
                                             unsigned short* __restrict__ Wvt) {
  int o = blockIdx.x*256 + threadIdx.x;  // o = v*128 + k
  int v = o >> 7, k = o & 127;
  float val = (v < VV) ? Wv[(size_t)k*VV + v] : 0.f;
  Wvt[o] = f2bf(val);
}

// K3: xb[r][j] = b_ih[j]+b_hh[j] + sum_k embed[cap_in[r]][k] * W_ih[j][k]
// 4 rows per thread to reuse each W element 4x.
__global__ __launch_bounds__(256) void k_xb(const int* __restrict__ captions,
    const float* __restrict__ embed, const float* __restrict__ Wt,
    const float* __restrict__ bih, const float* __restrict__ bhh,
    float* __restrict__ xb) {
  int g = blockIdx.x*256 + threadIdx.x;   // 262144 threads
  int j = g & 127;
  int rq = g >> 7;                         // 0..2047
  int r0 = rq, r1 = rq + 2048, r2 = rq + 4096, r3 = rq + 6144;
  const float* x0 = embed + (size_t)captions[(r0>>6)*65 + (r0&63)] * WVD;
  const float* x1 = embed + (size_t)captions[(r1>>6)*65 + (r1&63)] * WVD;
  const float* x2 = embed + (size_t)captions[(r2>>6)*65 + (r2&63)] * WVD;
  const float* x3 = embed + (size_t)captions[(r3>>6)*65 + (r3&63)] * WVD;
  float b = bih[j] + bhh[j];
  float a0 = b, a1 = b, a2 = b, a3 = b;
  #pragma unroll 4
  for (int k = 0; k < WVD; ++k) {
    float w = Wt[k*HH + j];                // coalesced over j, L1/L2 hot
    a0 += x0[k]*w; a1 += x1[k]*w; a2 += x2[k]*w; a3 += x3[k]*w;
  }
  xb[(size_t)r0*HH + j] = a0;
  xb[(size_t)r1*HH + j] = a1;
  xb[(size_t)r2*HH + j] = a2;
  xb[(size_t)r3*HH + j] = a3;
}

// K4: the sequential RNN. One block per sample n (independent over batch).
// W_hh staged in LDS padded to 129 floats/row -> conflict-free reads.
// 256 threads: thread (j, half) computes half the K-dot, LDS tree combine.
__global__ __launch_bounds__(256) void k_rnn(const float* __restrict__ h0,
    const float* __restrict__ xb, const float* __restrict__ Whh,
    float* __restrict__ hs) {
  __shared__ float Wh[HH*129];
  __shared__ float hcur[HH];
  __shared__ float part[256];
  int n = blockIdx.x, tid = threadIdx.x;
  for (int i = tid; i < HH*HH; i += 256) {
    int r = i >> 7, c = i & 127;
    Wh[r*129 + c] = Whh[i];
  }
  if (tid < HH) hcur[tid] = h0[n*HH + tid];
  __syncthreads();
  int j = tid & 127, half = tid >> 7, kb = half*64;
  const float* wr = &Wh[j*129 + kb];
  for (int t = 0; t < TT; ++t) {
    float s0 = 0.f, s1 = 0.f;
    const float* hr = &hcur[kb];
    #pragma unroll 8
    for (int k = 0; k < 64; k += 2) { s0 += hr[k]*wr[k]; s1 += hr[k+1]*wr[k+1]; }
    part[tid] = s0 + s1;
    __syncthreads();
    if (tid < HH) {
      float v = part[tid] + part[tid+128] + xb[(size_t)(n*TT + t)*HH + tid];
      float h = tanhf(v);
      hcur[tid] = h;
      hs[(size_t)(n*TT + t)*HH + tid] = h;
    }
    __syncthreads();
  }
}

// K5: fused scores + log-softmax + target NLL + masked mean.
// 256 blocks x 32 rows. 4 waves: wave = (rowhalf rh, colpair cp).
// A (h rows, bf16) held in registers; B (W_vocab cols) staged in
// XOR-swizzled LDS; mfma 16x16x32 bf16; epilogue: running sum-exp +
// target-score capture per lane, then shfl + LDS reduce + atomicAdd.
__global__ __launch_bounds__(256) void k_loss(const float* __restrict__ hs,
    const unsigned short* __restrict__ wvt, const float* __restrict__ bv,
    const int* __restrict__ captions, float* __restrict__ out) {
  __shared__ unsigned short bt[64*128];     // 16 KB, swizzled
  __shared__ float red[4][4][4][2];
  int tid = threadIdx.x;
  int w = tid >> 6, l = tid & 63;
  int l4 = l >> 4, lc = l & 15;
  int rowbase = blockIdx.x * 32;
  int rh = w >> 1, cp = w & 1;
  int arow = rowbase + rh*16 + lc;          // A-fragment row (l&15)

  short8 af[4];
  #pragma unroll
  for (int ks = 0; ks < 4; ++ks) {
    const float* p = hs + (size_t)arow*HH + ks*32 + l4*8;
    f32x4 x0 = *(const f32x4*)p;
    f32x4 x1 = *(const f32x4*)(p + 4);
    short8 t;
    t[0]=(short)f2bf(x0[0]); t[1]=(short)f2bf(x0[1]);
    t[2]=(short)f2bf(x0[2]); t[3]=(short)f2bf(x0[3]);
    t[4]=(short)f2bf(x1[0]); t[5]=(short)f2bf(x1[1]);
    t[6]=(short)f2bf(x1[2]); t[7]=(short)f2bf(x1[3]);
    af[ks] = t;
  }
  int tgt[4];
  #pragma unroll
  for (int jj = 0; jj < 4; ++jj) {
    int r = rowbase + rh*16 + l4*4 + jj;    // C/D row = (lane>>4)*4 + reg
    int n = r >> 6, t = r & 63;
    tgt[jj] = captions[n*65 + t + 1];
  }
  float se[4] = {0,0,0,0}, ts[4] = {0,0,0,0};

  for (int vs = 0; vs < VP/64; ++vs) {
    int vbase = vs*64;
    __syncthreads();
    #pragma unroll
    for (int i = 0; i < 4; ++i) {
      int chunk = i*256 + tid;              // 1024 x 16B
      int c = chunk >> 4, k8 = chunk & 15;
      u32x4 gv = *(const u32x4*)(wvt + (size_t)(vbase + c)*HH + k8*8);
      int byte = c*256 + ((k8*16) ^ ((c & 7) << 4));
      *(u32x4*)((char*)bt + byte) = gv;
    }
    __syncthreads();
    #pragma unroll
    for (int st2 = 0; st2 < 2; ++st2) {
      int st = cp*2 + st2;
      int c = st*16 + lc;                   // B col within 64-stage
      f32x4 acc = {0.f, 0.f, 0.f, 0.f};
      #pragma unroll
      for (int ks = 0; ks < 4; ++ks) {
        int byte = c*256 + (((ks*4 + l4)*16) ^ ((c & 7) << 4));
        short8 bf = *(const short8*)((const char*)bt + byte);
        acc = __builtin_amdgcn_mfma_f32_16x16x32_bf16(af[ks], bf, acc, 0, 0, 0);
      }
      int col = vbase + st*16 + lc;
      bool valid = col < VV;
      float bvv = valid ? bv[col] : 0.f;
      #pragma unroll
      for (int jj = 0; jj < 4; ++jj) {
        float s = acc[jj] + bvv;
        if (valid) {
          se[jj] += __expf(s);
          if (col == tgt[jj]) ts[jj] = s;
        }
      }
    }
  }
  #pragma unroll
  for (int jj = 0; jj < 4; ++jj) {
    #pragma unroll
    for (int m = 1; m < 16; m <<= 1) {
      se[jj] += __shfl_xor(se[jj], m);
      ts[jj] += __shfl_xor(ts[jj], m);
    }
  }
  if (lc == 0) {
    #pragma unroll
    for (int jj = 0; jj < 4; ++jj) {
      red[w][l4][jj][0] = se[jj];
      red[w][l4][jj][1] = ts[jj];
    }
  }
  __syncthreads();
  if (tid < 32) {
    int r = tid, rh2 = r >> 4, rr = r & 15, g = rr >> 2, jj = rr & 3;
    float sesum = red[rh2*2][g][jj][0] + red[rh2*2+1][g][jj][0];
    float tssum = red[rh2*2][g][jj][1] + red[rh2*2+1][g][jj][1];
    int row = rowbase + r;
    int n = row >> 6, t = row & 63;
    int tg = captions[n*65 + t + 1];
    if (tg != 0) {
      float nll = logf(sesum) - tssum;
      atomicAdd(out, nll * (1.0f/128.0f));
    }
  }
}

extern "C" void kernel_launch(void* const* d_in, const int* in_sizes, int n_in,
                              void* d_out, int out_size, void* d_ws, size_t ws_size,
                              hipStream_t stream) {
  const float* features = (const float*)d_in[0];
  const int*   captions = (const int*)d_in[1];
  const float* W_proj   = (const float*)d_in[2];
  const float* b_proj   = (const float*)d_in[3];
  const float* embed    = (const float*)d_in[4];
  const float* W_ih     = (const float*)d_in[5];
  const float* W_hh     = (const float*)d_in[6];
  const float* b_ih     = (const float*)d_in[7];
  const float* b_hh     = (const float*)d_in[8];
  const float* W_vocab  = (const float*)d_in[9];
  const float* b_vocab  = (const float*)d_in[10];
  float* out = (float*)d_out;
  char* ws = (char*)d_ws;

  float* h0    = (float*)(ws);                          // 64 KB
  float* xb    = (float*)(ws + 65536);                  // 4 MB
  float* hs    = (float*)(ws + 65536 + 4194304);        // 4 MB
  float* wih_t = (float*)(ws + 65536 + 8388608);        // 64 KB
  unsigned short* wvt = (unsigned short*)(ws + 131072 + 8388608); // 2.57 MB

  hipLaunchKernelGGL(k_h0,  dim3(NB), dim3(HH), 0, stream, features, W_proj, b_proj, h0, out);
  hipLaunchKernelGGL(k_twih, dim3((HH*WVD)/256), dim3(256), 0, stream, W_ih, wih_t);
  hipLaunchKernelGGL(k_twv,  dim3((VP*HH)/256), dim3(256), 0, stream, W_vocab, wvt);
  hipLaunchKernelGGL(k_xb,   dim3((NROW*HH/4)/256), dim3(256), 0, stream, captions, embed, wih_t, b_ih, b_hh, xb);
  hipLaunchKernelGGL(k_rnn,  dim3(NB), dim3(256), 0, stream, h0, xb, W_hh, hs);
  hipLaunchKernelGGL(k_loss, dim3(NROW/32), dim3(256), 0, stream, hs, wvt, b_vocab, captions, out);
}

// Round 3
// 210.781 us; speedup vs baseline: 1.5706x; 1.5685x over previous
//
#include <hip/hip_runtime.h>
#include <hip/hip_bf16.h>
#include <math.h>

typedef __attribute__((ext_vector_type(8))) short short8;
typedef __attribute__((ext_vector_type(4))) float f32x4;
typedef __attribute__((ext_vector_type(4))) unsigned int u32x4;

#define NB   128   // batch
#define TT   64    // timesteps (T-1)
#define DD   512   // feature dim
#define HH   128   // hidden dim
#define WVD  128   // wordvec dim
#define VV   10000 // vocab
#define VP   10048 // vocab padded to multiple of 64
#define NROW (NB*TT)
#define NSTRIP (VP/16)   // 628 column strips of 16
#define VSPLIT 64        // V-slices per row-block
#define LOG2E 1.44269504088896f
#define LN2   0.69314718055995f

__device__ __forceinline__ unsigned short f2bf(float x) {
  union { float f; unsigned int u; } v; v.f = x;
  unsigned int r = v.u + 0x7fffu + ((v.u >> 16) & 1u);
  return (unsigned short)(r >> 16);
}
__device__ __forceinline__ float bf2f(unsigned short u) {
  union { unsigned int i; float f; } v; v.i = ((unsigned int)u) << 16; return v.f;
}

// K0: h0 = features @ W_proj + b_proj
__global__ __launch_bounds__(128) void k_h0(const float* __restrict__ features,
    const float* __restrict__ Wp, const float* __restrict__ bp,
    float* __restrict__ h0) {
  __shared__ float fl[DD];
  int n = blockIdx.x, j = threadIdx.x;
  for (int k = j; k < DD; k += HH) fl[k] = features[n*DD + k];
  __syncthreads();
  float s = bp[j];
  #pragma unroll 4
  for (int k = 0; k < DD; ++k) s += fl[k] * Wp[k*HH + j];  // coalesced over j
  h0[n*HH + j] = s;
}

// K1: Wih_t[k][j] = W_ih[j][k]
__global__ __launch_bounds__(256) void k_twih(const float* __restrict__ Wih,
                                              float* __restrict__ Wt) {
  int o = blockIdx.x*256 + threadIdx.x;
  int k = o >> 7, j = o & 127;
  Wt[o] = Wih[j*WVD + k];
}

// K2: Wvt[v][k] = bf16(W_vocab[k][v]), zero-padded rows v in [VV, VP)
__global__ __launch_bounds__(256) void k_twv(const float* __restrict__ Wv,
                                             unsigned short* __restrict__ Wvt) {
  int o = blockIdx.x*256 + threadIdx.x;
  int v = o >> 7, k = o & 127;
  float val = (v < VV) ? Wv[(size_t)k*VV + v] : 0.f;
  Wvt[o] = f2bf(val);
}

// K2b: expbv[v] = exp(b_vocab[v]), 0 for pad (kills validity branch in k_loss)
__global__ __launch_bounds__(256) void k_expbv(const float* __restrict__ bv,
                                               float* __restrict__ expbv) {
  int v = blockIdx.x*256 + threadIdx.x;
  if (v < VP) expbv[v] = (v < VV) ? __expf(bv[v]) : 0.f;
}

// K3: xb[r][j] = b_ih[j]+b_hh[j] + sum_k embed[cap_in[r]][k] * W_ih[j][k]
__global__ __launch_bounds__(256) void k_xb(const int* __restrict__ captions,
    const float* __restrict__ embed, const float* __restrict__ Wt,
    const float* __restrict__ bih, const float* __restrict__ bhh,
    float* __restrict__ xb) {
  int g = blockIdx.x*256 + threadIdx.x;
  int j = g & 127;
  int rq = g >> 7;
  int r0 = rq, r1 = rq + 2048, r2 = rq + 4096, r3 = rq + 6144;
  const float* x0 = embed + (size_t)captions[(r0>>6)*65 + (r0&63)] * WVD;
  const float* x1 = embed + (size_t)captions[(r1>>6)*65 + (r1&63)] * WVD;
  const float* x2 = embed + (size_t)captions[(r2>>6)*65 + (r2&63)] * WVD;
  const float* x3 = embed + (size_t)captions[(r3>>6)*65 + (r3&63)] * WVD;
  float b = bih[j] + bhh[j];
  float a0 = b, a1 = b, a2 = b, a3 = b;
  #pragma unroll 4
  for (int k = 0; k < WVD; ++k) {
    float w = Wt[k*HH + j];
    a0 += x0[k]*w; a1 += x1[k]*w; a2 += x2[k]*w; a3 += x3[k]*w;
  }
  xb[(size_t)r0*HH + j] = a0;
  xb[(size_t)r1*HH + j] = a1;
  xb[(size_t)r2*HH + j] = a2;
  xb[(size_t)r3*HH + j] = a3;
}

// K4: sequential RNN, one block per sample. fp32 recurrence; stores h as
// bf16 PRE-SCALED by log2e (so the loss GEMM accumulates log2-domain scores).
__global__ __launch_bounds__(256) void k_rnn(const float* __restrict__ h0,
    const float* __restrict__ xb, const float* __restrict__ Whh,
    unsigned short* __restrict__ hsb) {
  __shared__ float Wh[HH*129];
  __shared__ float hcur[HH];
  __shared__ float part[256];
  int n = blockIdx.x, tid = threadIdx.x;
  for (int i = tid; i < HH*HH; i += 256) {
    int r = i >> 7, c = i & 127;
    Wh[r*129 + c] = Whh[i];
  }
  if (tid < HH) hcur[tid] = h0[n*HH + tid];
  __syncthreads();
  int j = tid & 127, half = tid >> 7, kb = half*64;
  const float* wr = &Wh[j*129 + kb];
  for (int t = 0; t < TT; ++t) {
    float s0 = 0.f, s1 = 0.f;
    const float* hr = &hcur[kb];
    #pragma unroll 8
    for (int k = 0; k < 64; k += 2) { s0 += hr[k]*wr[k]; s1 += hr[k+1]*wr[k+1]; }
    part[tid] = s0 + s1;
    __syncthreads();
    if (tid < HH) {
      float v = part[tid] + part[tid+128] + xb[(size_t)(n*TT + t)*HH + tid];
      float h = tanhf(v);
      hcur[tid] = h;
      hsb[(size_t)(n*TT + t)*HH + tid] = f2bf(h * LOG2E);
    }
    __syncthreads();
  }
}

// K5: sum-exp of scores. Barrier-free, LDS-free.
// Grid = 32 row-blocks x 64 V-slices. Block = 4 waves; wave owns 64 rows
// (A-frags in 64 VGPRs, loaded once). B-frags loaded straight from global in
// MFMA layout — 4 waves of a block read the same strip => L1 reuse.
// Epilogue per element: se += exp2(acc) * expbv[col]  (1 v_exp + 1 v_fma).
// Per-row partial Sigma-exp -> shfl reduce -> atomicAdd into se_acc.
__global__ __launch_bounds__(256) void k_loss(
    const unsigned short* __restrict__ hsb,
    const unsigned short* __restrict__ wvt,
    const float* __restrict__ expbv,
    float* __restrict__ se_acc) {
  int tid = threadIdx.x;
  int w = tid >> 6, l = tid & 63;
  int l4 = l >> 4, lc = l & 15;
  int rb = blockIdx.x & 31;     // row-block: 256 rows
  int vb = blockIdx.x >> 5;     // V-slice: strips vb, vb+64, ...
  int wrow = rb*256 + w*64;     // this wave's 64 rows

  short8 af[4][4];
  #pragma unroll
  for (int sm = 0; sm < 4; ++sm)
    #pragma unroll
    for (int ks = 0; ks < 4; ++ks)
      af[sm][ks] = *(const short8*)(hsb + (size_t)(wrow + sm*16 + lc)*HH + ks*32 + l4*8);

  float se[4][4] = {{0.f}};
  for (int s = vb; s < NSTRIP; s += VSPLIT) {
    int vbase = s*16;
    short8 bf[4];
    #pragma unroll
    for (int ks = 0; ks < 4; ++ks)
      bf[ks] = *(const short8*)(wvt + (size_t)(vbase + lc)*HH + ks*32 + l4*8);
    float eb = expbv[vbase + lc];
    #pragma unroll
    for (int sm = 0; sm < 4; ++sm) {
      f32x4 acc = {0.f, 0.f, 0.f, 0.f};
      #pragma unroll
      for (int ks = 0; ks < 4; ++ks)
        acc = __builtin_amdgcn_mfma_f32_16x16x32_bf16(af[sm][ks], bf[ks], acc, 0, 0, 0);
      #pragma unroll
      for (int jj = 0; jj < 4; ++jj)
        se[sm][jj] += __builtin_amdgcn_exp2f(acc[jj]) * eb;
    }
  }
  #pragma unroll
  for (int sm = 0; sm < 4; ++sm)
    #pragma unroll
    for (int jj = 0; jj < 4; ++jj) {
      float v = se[sm][jj];
      v += __shfl_xor(v, 1); v += __shfl_xor(v, 2);
      v += __shfl_xor(v, 4); v += __shfl_xor(v, 8);
      se[sm][jj] = v;
    }
  if (lc == 0) {
    #pragma unroll
    for (int sm = 0; sm < 4; ++sm)
      #pragma unroll
      for (int jj = 0; jj < 4; ++jj)
        atomicAdd(&se_acc[wrow + sm*16 + l4*4 + jj], se[sm][jj]);
  }
}

// K6: per-row target score + masked NLL reduction.
// ts = (hsb_row . wvt[tgt]) * ln2 + bv[tgt]  (hsb is log2e-scaled)
__global__ __launch_bounds__(256) void k_final(
    const unsigned short* __restrict__ hsb,
    const unsigned short* __restrict__ wvt,
    const float* __restrict__ bv,
    const float* __restrict__ se_acc,
    const int* __restrict__ captions,
    float* __restrict__ out) {
  int tid = threadIdx.x;
  int w = tid >> 6, l = tid & 63;
  int row = blockIdx.x*32 + w*8 + (l >> 3);
  int seg = l & 7;
  int n = row >> 6, t = row & 63;
  int tg = captions[n*65 + t + 1];
  float part = 0.f;
  if (tg != 0) {
    const unsigned short* a = hsb + (size_t)row*HH + seg*16;
    const unsigned short* b = wvt + (size_t)tg*HH + seg*16;
    short8 a0 = *(const short8*)a, a1 = *(const short8*)(a+8);
    short8 b0 = *(const short8*)b, b1 = *(const short8*)(b+8);
    #pragma unroll
    for (int i = 0; i < 8; ++i) {
      part += bf2f((unsigned short)a0[i]) * bf2f((unsigned short)b0[i]);
      part += bf2f((unsigned short)a1[i]) * bf2f((unsigned short)b1[i]);
    }
  }
  part += __shfl_xor(part, 1);
  part += __shfl_xor(part, 2);
  part += __shfl_xor(part, 4);
  if (seg == 0 && tg != 0) {
    float score = part * LN2 + bv[tg];
    float nll = logf(se_acc[row]) - score;
    atomicAdd(out, nll * (1.0f/128.0f));
  }
}

extern "C" void kernel_launch(void* const* d_in, const int* in_sizes, int n_in,
                              void* d_out, int out_size, void* d_ws, size_t ws_size,
                              hipStream_t stream) {
  const float* features = (const float*)d_in[0];
  const int*   captions = (const int*)d_in[1];
  const float* W_proj   = (const float*)d_in[2];
  const float* b_proj   = (const float*)d_in[3];
  const float* embed    = (const float*)d_in[4];
  const float* W_ih     = (const float*)d_in[5];
  const float* W_hh     = (const float*)d_in[6];
  const float* b_ih     = (const float*)d_in[7];
  const float* b_hh     = (const float*)d_in[8];
  const float* W_vocab  = (const float*)d_in[9];
  const float* b_vocab  = (const float*)d_in[10];
  float* out = (float*)d_out;
  char* ws = (char*)d_ws;

  float*          h0     = (float*)(ws + 0x000000);            // 64 KB
  float*          xb     = (float*)(ws + 0x010000);            // 4 MB
  unsigned short* hsb    = (unsigned short*)(ws + 0x410000);   // 2 MB
  float*          wih_t  = (float*)(ws + 0x610000);            // 64 KB
  unsigned short* wvt    = (unsigned short*)(ws + 0x620000);   // 2.57 MB
  float*          expbv  = (float*)(ws + 0x8A0000);            // 40 KB
  float*          se_acc = (float*)(ws + 0x8B0000);            // 32 KB

  hipMemsetAsync(se_acc, 0, NROW*sizeof(float), stream);
  hipMemsetAsync(out, 0, sizeof(float), stream);

  hipLaunchKernelGGL(k_h0,   dim3(NB), dim3(HH), 0, stream, features, W_proj, b_proj, h0);
  hipLaunchKernelGGL(k_twih, dim3((HH*WVD)/256), dim3(256), 0, stream, W_ih, wih_t);
  hipLaunchKernelGGL(k_twv,  dim3((VP*HH)/256), dim3(256), 0, stream, W_vocab, wvt);
  hipLaunchKernelGGL(k_expbv, dim3((VP+255)/256), dim3(256), 0, stream, b_vocab, expbv);
  hipLaunchKernelGGL(k_xb,   dim3((NROW*HH/4)/256), dim3(256), 0, stream, captions, embed, wih_t, b_ih, b_hh, xb);
  hipLaunchKernelGGL(k_rnn,  dim3(NB), dim3(256), 0, stream, h0, xb, W_hh, hsb);
  hipLaunchKernelGGL(k_loss, dim3(32*VSPLIT), dim3(256), 0, stream, hsb, wvt, expbv, se_acc);
  hipLaunchKernelGGL(k_final, dim3(NROW/32), dim3(256), 0, stream, hsb, wvt, b_vocab, se_acc, captions, out);
}

// Round 4
// 182.859 us; speedup vs baseline: 1.8104x; 1.1527x over previous
//
#include <hip/hip_runtime.h>
#include <hip/hip_bf16.h>
#include <math.h>

typedef __attribute__((ext_vector_type(8))) short short8;
typedef __attribute__((ext_vector_type(4))) float f32x4;
typedef __attribute__((ext_vector_type(4))) unsigned int u32x4;

#define NB   128   // batch
#define TT   64    // timesteps (T-1)
#define DD   512   // feature dim
#define HH   128   // hidden dim
#define WVD  128   // wordvec dim
#define VV   10000 // vocab
#define VP   10048 // vocab padded to multiple of 64
#define NROW (NB*TT)
#define NSTRIP (VP/16)   // 628 column strips of 16
#define VSPLIT 64        // V-slices per row-block
#define LOG2E 1.44269504088896f
#define LN2   0.69314718055995f

__device__ __forceinline__ unsigned short f2bf(float x) {
  union { float f; unsigned int u; } v; v.f = x;
  unsigned int r = v.u + 0x7fffu + ((v.u >> 16) & 1u);
  return (unsigned short)(r >> 16);
}
__device__ __forceinline__ float bf2f(unsigned short u) {
  union { unsigned int i; float f; } v; v.i = ((unsigned int)u) << 16; return v.f;
}

// K0: h0 = features @ W_proj + b_proj
__global__ __launch_bounds__(128) void k_h0(const float* __restrict__ features,
    const float* __restrict__ Wp, const float* __restrict__ bp,
    float* __restrict__ h0) {
  __shared__ float fl[DD];
  int n = blockIdx.x, j = threadIdx.x;
  for (int k = j; k < DD; k += HH) fl[k] = features[n*DD + k];
  __syncthreads();
  float s = bp[j];
  #pragma unroll 4
  for (int k = 0; k < DD; ++k) s += fl[k] * Wp[k*HH + j];  // coalesced over j
  h0[n*HH + j] = s;
}

// K1: Wih_t[k][j] = W_ih[j][k]
__global__ __launch_bounds__(256) void k_twih(const float* __restrict__ Wih,
                                              float* __restrict__ Wt) {
  int o = blockIdx.x*256 + threadIdx.x;
  int k = o >> 7, j = o & 127;
  Wt[o] = Wih[j*WVD + k];
}

// K2: Wvt[v][k] = bf16(W_vocab[k][v]) via 64x64 LDS tile transpose.
// Both global phases coalesced; zero-pads rows v in [VV, VP).
__global__ __launch_bounds__(256) void k_twv(const float* __restrict__ Wv,
                                             unsigned short* __restrict__ Wvt) {
  __shared__ float tile[64][65];
  int bv = (blockIdx.x >> 1) * 64;      // v tile base
  int bk = (blockIdx.x & 1) * 64;       // k tile base
  int tid = threadIdx.x;
  int tv = tid & 63;
  int tk0 = tid >> 6;                   // 0..3
  #pragma unroll
  for (int kk = 0; kk < 64; kk += 4) {
    int k = bk + kk + tk0;
    int v = bv + tv;
    tile[kk + tk0][tv] = (v < VV) ? Wv[(size_t)k*VV + v] : 0.f;
  }
  __syncthreads();
  int tk = tid & 63;
  int tv0 = tid >> 6;
  #pragma unroll
  for (int vv = 0; vv < 64; vv += 4) {
    int v = bv + vv + tv0;
    Wvt[(size_t)v*HH + bk + tk] = f2bf(tile[tk][vv + tv0]);
  }
}

// K2b: expbv[v] = exp(b_vocab[v]), 0 for pad
__global__ __launch_bounds__(256) void k_expbv(const float* __restrict__ bv,
                                               float* __restrict__ expbv) {
  int v = blockIdx.x*256 + threadIdx.x;
  if (v < VP) expbv[v] = (v < VV) ? __expf(bv[v]) : 0.f;
}

// K3: xb[r][j] = b_ih[j]+b_hh[j] + sum_k embed[cap_in[r]][k] * W_ih[j][k]
__global__ __launch_bounds__(256) void k_xb(const int* __restrict__ captions,
    const float* __restrict__ embed, const float* __restrict__ Wt,
    const float* __restrict__ bih, const float* __restrict__ bhh,
    float* __restrict__ xb) {
  int g = blockIdx.x*256 + threadIdx.x;
  int j = g & 127;
  int rq = g >> 7;
  int r0 = rq, r1 = rq + 2048, r2 = rq + 4096, r3 = rq + 6144;
  const float* x0 = embed + (size_t)captions[(r0>>6)*65 + (r0&63)] * WVD;
  const float* x1 = embed + (size_t)captions[(r1>>6)*65 + (r1&63)] * WVD;
  const float* x2 = embed + (size_t)captions[(r2>>6)*65 + (r2&63)] * WVD;
  const float* x3 = embed + (size_t)captions[(r3>>6)*65 + (r3&63)] * WVD;
  float b = bih[j] + bhh[j];
  float a0 = b, a1 = b, a2 = b, a3 = b;
  #pragma unroll 4
  for (int k = 0; k < WVD; ++k) {
    float w = Wt[k*HH + j];
    a0 += x0[k]*w; a1 += x1[k]*w; a2 += x2[k]*w; a3 += x3[k]*w;
  }
  xb[(size_t)r0*HH + j] = a0;
  xb[(size_t)r1*HH + j] = a1;
  xb[(size_t)r2*HH + j] = a2;
  xb[(size_t)r3*HH + j] = a3;
}

// K4: sequential RNN, one block (4 waves) per sample.
// Loop is LDS+VALU only: W_hh row-half in registers (64 VGPR/lane),
// xb slice pre-staged to LDS, h history accumulated in LDS and flushed
// coalesced at the end. Wave w owns j in [32w,32w+32); lane l handles
// (j = 32w + (l&31), K-half = l>>5); K-reduce = one shfl_xor(32).
// Double-buffered hbuf -> exactly 1 barrier per step.
__global__ __launch_bounds__(256) void k_rnn(const float* __restrict__ h0,
    const float* __restrict__ xb, const float* __restrict__ Whh,
    unsigned short* __restrict__ hsb) {
  __shared__ float xl[TT][HH];            // 32 KB
  __shared__ unsigned short hl[TT][HH];   // 16 KB
  __shared__ float hbuf[2][HH];           // 1 KB
  int n = blockIdx.x, tid = threadIdx.x;
  int w = tid >> 6, l = tid & 63;
  int j = w*32 + (l & 31);
  int kb = (l >> 5) * 64;

  // stage xb slice (coalesced 16B)
  const float* xsrc = xb + (size_t)n*TT*HH;
  #pragma unroll
  for (int it = 0; it < 8; ++it) {
    int o = it*256 + tid;                 // f32x4 index
    *(f32x4*)(&xl[0][0] + o*4) = *(const f32x4*)(xsrc + o*4);
  }
  // W_hh[j][kb..kb+63] into registers
  float wr_[64];
  const float* wsrc = Whh + (size_t)j*HH + kb;
  #pragma unroll
  for (int i = 0; i < 16; ++i) {
    f32x4 v = *(const f32x4*)(wsrc + i*4);
    wr_[i*4+0]=v[0]; wr_[i*4+1]=v[1]; wr_[i*4+2]=v[2]; wr_[i*4+3]=v[3];
  }
  if (tid < HH) hbuf[0][tid] = h0[n*HH + tid];
  __syncthreads();

  int cur = 0;
  for (int t = 0; t < TT; ++t) {
    float s0=0.f, s1=0.f, s2=0.f, s3=0.f;
    const float* hr = &hbuf[cur][kb];
    #pragma unroll
    for (int i = 0; i < 16; ++i) {
      f32x4 hv = *(const f32x4*)(hr + i*4);   // 2-addr broadcast, conflict-free
      s0 += hv[0]*wr_[i*4+0]; s1 += hv[1]*wr_[i*4+1];
      s2 += hv[2]*wr_[i*4+2]; s3 += hv[3]*wr_[i*4+3];
    }
    float s = (s0+s1)+(s2+s3);
    s += __shfl_xor(s, 32);                   // combine the two K-halves
    float v = s + xl[t][j];
    float e = __builtin_amdgcn_exp2f(v * (2.0f*LOG2E));
    float h = 1.0f - 2.0f*__builtin_amdgcn_rcpf(e + 1.0f);  // tanh
    if (l < 32) {
      hbuf[cur^1][j] = h;
      hl[t][j] = f2bf(h * LOG2E);
    }
    __syncthreads();
    cur ^= 1;
  }
  // flush h history -> global (coalesced 16B)
  unsigned short* dst = hsb + (size_t)n*TT*HH;
  #pragma unroll
  for (int it = 0; it < 4; ++it) {
    int o = it*256 + tid;                 // 16B chunk index
    *(u32x4*)(dst + o*8) = *(const u32x4*)(&hl[0][0] + o*8);
  }
}

// K5: sum-exp of scores. Barrier-free, LDS-free.
// Grid = 32 row-blocks x 64 V-slices. Block = 4 waves; wave owns 64 rows
// (A-frags in 64 VGPRs, loaded once). B-frags loaded straight from global in
// MFMA layout — 4 waves of a block read the same strip => L1 reuse.
__global__ __launch_bounds__(256) void k_loss(
    const unsigned short* __restrict__ hsb,
    const unsigned short* __restrict__ wvt,
    const float* __restrict__ expbv,
    float* __restrict__ se_acc) {
  int tid = threadIdx.x;
  int w = tid >> 6, l = tid & 63;
  int l4 = l >> 4, lc = l & 15;
  int rb = blockIdx.x & 31;     // row-block: 256 rows
  int vb = blockIdx.x >> 5;     // V-slice
  int wrow = rb*256 + w*64;     // this wave's 64 rows

  short8 af[4][4];
  #pragma unroll
  for (int sm = 0; sm < 4; ++sm)
    #pragma unroll
    for (int ks = 0; ks < 4; ++ks)
      af[sm][ks] = *(const short8*)(hsb + (size_t)(wrow + sm*16 + lc)*HH + ks*32 + l4*8);

  float se[4][4] = {{0.f}};
  for (int s = vb; s < NSTRIP; s += VSPLIT) {
    int vbase = s*16;
    short8 bf[4];
    #pragma unroll
    for (int ks = 0; ks < 4; ++ks)
      bf[ks] = *(const short8*)(wvt + (size_t)(vbase + lc)*HH + ks*32 + l4*8);
    float eb = expbv[vbase + lc];
    #pragma unroll
    for (int sm = 0; sm < 4; ++sm) {
      f32x4 acc = {0.f, 0.f, 0.f, 0.f};
      #pragma unroll
      for (int ks = 0; ks < 4; ++ks)
        acc = __builtin_amdgcn_mfma_f32_16x16x32_bf16(af[sm][ks], bf[ks], acc, 0, 0, 0);
      #pragma unroll
      for (int jj = 0; jj < 4; ++jj)
        se[sm][jj] += __builtin_amdgcn_exp2f(acc[jj]) * eb;
    }
  }
  #pragma unroll
  for (int sm = 0; sm < 4; ++sm)
    #pragma unroll
    for (int jj = 0; jj < 4; ++jj) {
      float v = se[sm][jj];
      v += __shfl_xor(v, 1); v += __shfl_xor(v, 2);
      v += __shfl_xor(v, 4); v += __shfl_xor(v, 8);
      se[sm][jj] = v;
    }
  if (lc == 0) {
    #pragma unroll
    for (int sm = 0; sm < 4; ++sm)
      #pragma unroll
      for (int jj = 0; jj < 4; ++jj)
        atomicAdd(&se_acc[wrow + sm*16 + l4*4 + jj], se[sm][jj]);
  }
}

// K6: per-row target score + masked NLL reduction.
__global__ __launch_bounds__(256) void k_final(
    const unsigned short* __restrict__ hsb,
    const unsigned short* __restrict__ wvt,
    const float* __restrict__ bv,
    const float* __restrict__ se_acc,
    const int* __restrict__ captions,
    float* __restrict__ out) {
  int tid = threadIdx.x;
  int w = tid >> 6, l = tid & 63;
  int row = blockIdx.x*32 + w*8 + (l >> 3);
  int seg = l & 7;
  int n = row >> 6, t = row & 63;
  int tg = captions[n*65 + t + 1];
  float part = 0.f;
  if (tg != 0) {
    const unsigned short* a = hsb + (size_t)row*HH + seg*16;
    const unsigned short* b = wvt + (size_t)tg*HH + seg*16;
    short8 a0 = *(const short8*)a, a1 = *(const short8*)(a+8);
    short8 b0 = *(const short8*)b, b1 = *(const short8*)(b+8);
    #pragma unroll
    for (int i = 0; i < 8; ++i) {
      part += bf2f((unsigned short)a0[i]) * bf2f((unsigned short)b0[i]);
      part += bf2f((unsigned short)a1[i]) * bf2f((unsigned short)b1[i]);
    }
  }
  part += __shfl_xor(part, 1);
  part += __shfl_xor(part, 2);
  part += __shfl_xor(part, 4);
  if (seg == 0 && tg != 0) {
    float score = part * LN2 + bv[tg];
    float nll = logf(se_acc[row]) - score;
    atomicAdd(out, nll * (1.0f/128.0f));
  }
}

extern "C" void kernel_launch(void* const* d_in, const int* in_sizes, int n_in,
                              void* d_out, int out_size, void* d_ws, size_t ws_size,
                              hipStream_t stream) {
  const float* features = (const float*)d_in[0];
  const int*   captions = (const int*)d_in[1];
  const float* W_proj   = (const float*)d_in[2];
  const float* b_proj   = (const float*)d_in[3];
  const float* embed    = (const float*)d_in[4];
  const float* W_ih     = (const float*)d_in[5];
  const float* W_hh     = (const float*)d_in[6];
  const float* b_ih     = (const float*)d_in[7];
  const float* b_hh     = (const float*)d_in[8];
  const float* W_vocab  = (const float*)d_in[9];
  const float* b_vocab  = (const float*)d_in[10];
  float* out = (float*)d_out;
  char* ws = (char*)d_ws;

  float*          h0     = (float*)(ws + 0x000000);            // 64 KB
  float*          xb     = (float*)(ws + 0x010000);            // 4 MB
  unsigned short* hsb    = (unsigned short*)(ws + 0x410000);   // 2 MB
  float*          wih_t  = (float*)(ws + 0x610000);            // 64 KB
  unsigned short* wvt    = (unsigned short*)(ws + 0x620000);   // 2.57 MB
  float*          expbv  = (float*)(ws + 0x8A0000);            // 40 KB
  float*          se_acc = (float*)(ws + 0x8B0000);            // 32 KB

  hipMemsetAsync(se_acc, 0, NROW*sizeof(float), stream);
  hipMemsetAsync(out, 0, sizeof(float), stream);

  hipLaunchKernelGGL(k_h0,   dim3(NB), dim3(HH), 0, stream, features, W_proj, b_proj, h0);
  hipLaunchKernelGGL(k_twih, dim3((HH*WVD)/256), dim3(256), 0, stream, W_ih, wih_t);
  hipLaunchKernelGGL(k_twv,  dim3((VP/64)*2), dim3(256), 0, stream, W_vocab, wvt);
  hipLaunchKernelGGL(k_expbv, dim3((VP+255)/256), dim3(256), 0, stream, b_vocab, expbv);
  hipLaunchKernelGGL(k_xb,   dim3((NROW*HH/4)/256), dim3(256), 0, stream, captions, embed, wih_t, b_ih, b_hh, xb);
  hipLaunchKernelGGL(k_rnn,  dim3(NB), dim3(256), 0, stream, h0, xb, W_hh, hsb);
  hipLaunchKernelGGL(k_loss, dim3(32*VSPLIT), dim3(256), 0, stream, hsb, wvt, expbv, se_acc);
  hipLaunchKernelGGL(k_final, dim3(NROW/32), dim3(256), 0, stream, hsb, wvt, b_vocab, se_acc, captions, out);
}

// Round 5
// 140.071 us; speedup vs baseline: 2.3634x; 1.3055x over previous
//
#include <hip/hip_runtime.h>
#include <hip/hip_bf16.h>
#include <math.h>

typedef __attribute__((ext_vector_type(8))) short short8;
typedef __attribute__((ext_vector_type(4))) float f32x4;
typedef __attribute__((ext_vector_type(4))) unsigned int u32x4;

#define NB   128   // batch
#define TT   64    // timesteps (T-1)
#define DD   512   // feature dim
#define HH   128   // hidden dim
#define WVD  128   // wordvec dim
#define VV   10000 // vocab
#define VP   10048 // vocab padded to multiple of 64
#define NROW (NB*TT)
#define NSTRIP (VP/16)   // 628 column strips of 16
#define VSPLIT 64        // V-slices per row-block
#define LOG2E 1.44269504088896f
#define LN2   0.69314718055995f

__device__ __forceinline__ unsigned short f2bf(float x) {
  union { float f; unsigned int u; } v; v.f = x;
  unsigned int r = v.u + 0x7fffu + ((v.u >> 16) & 1u);
  return (unsigned short)(r >> 16);
}
__device__ __forceinline__ float bf2f(unsigned short u) {
  union { unsigned int i; float f; } v; v.i = ((unsigned int)u) << 16; return v.f;
}

// ---------------------------------------------------------------------------
// K_prep: fused prep. Blocks:
//   [0,314)    : Wvt[v][k] = bf16(W_vocab[k][v])  (64x64 LDS tile transpose)
//   [314,378)  : Wt[k*128+j] = W_ih[j][k]
//   [378,418)  : expbv[v] = exp(b_vocab[v]) (0 for pad)
//   [418,426)  : se_acc = 0
//   426        : out = 0
// ---------------------------------------------------------------------------
__global__ __launch_bounds__(256) void k_prep(
    const float* __restrict__ Wv, unsigned short* __restrict__ Wvt,
    const float* __restrict__ Wih, float* __restrict__ Wt,
    const float* __restrict__ bv, float* __restrict__ expbv,
    float* __restrict__ se_acc, float* __restrict__ out) {
  __shared__ float tile[64][65];
  int b = blockIdx.x, tid = threadIdx.x;
  if (b < 314) {
    int bvv = (b >> 1) * 64;            // v tile base
    int bk  = (b & 1) * 64;             // k tile base
    int tv = tid & 63;
    int tk0 = tid >> 6;                 // 0..3
    #pragma unroll
    for (int kk = 0; kk < 64; kk += 4) {
      int k = bk + kk + tk0;
      int v = bvv + tv;
      tile[kk + tk0][tv] = (v < VV) ? Wv[(size_t)k*VV + v] : 0.f;
    }
    __syncthreads();
    int tk = tid & 63;
    int tv0 = tid >> 6;
    #pragma unroll
    for (int vv = 0; vv < 64; vv += 4) {
      int v = bvv + vv + tv0;
      Wvt[(size_t)v*HH + bk + tk] = f2bf(tile[tk][vv + tv0]);
    }
  } else if (b < 378) {
    int o = (b - 314)*256 + tid;
    int k = o >> 7, j = o & 127;
    Wt[o] = Wih[j*WVD + k];
  } else if (b < 418) {
    int v = (b - 378)*256 + tid;
    if (v < VP) expbv[v] = (v < VV) ? __expf(bv[v]) : 0.f;
  } else if (b < 426) {
    int idx = (b - 418)*1024 + tid*4;
    f32x4 z = {0.f,0.f,0.f,0.f};
    *(f32x4*)(se_acc + idx) = z;
  } else {
    if (tid == 0) out[0] = 0.f;
  }
}

// ---------------------------------------------------------------------------
// K_h0: h0 = features @ W_proj + b_proj. One block (256 thr) per sample.
// Thread = (jq = 4-col quad, ks = 64-k slice); f32x4 loads; LDS reduce.
// ---------------------------------------------------------------------------
__global__ __launch_bounds__(256) void k_h0(const float* __restrict__ features,
    const float* __restrict__ Wp, const float* __restrict__ bp,
    float* __restrict__ h0) {
  __shared__ float fl[DD];
  __shared__ f32x4 red[8][32];
  int n = blockIdx.x, tid = threadIdx.x;
  fl[tid]       = features[n*DD + tid];
  fl[tid + 256] = features[n*DD + 256 + tid];
  __syncthreads();
  int jq = (tid & 31) * 4;
  int ks = tid >> 5;                    // 0..7
  f32x4 acc = {0.f,0.f,0.f,0.f};
  const float* wp = Wp + (size_t)(ks*64)*HH + jq;
  #pragma unroll 4
  for (int k = 0; k < 64; ++k) {
    f32x4 wv = *(const f32x4*)(wp + (size_t)k*HH);
    acc += fl[ks*64 + k] * wv;
  }
  red[ks][tid & 31] = acc;
  __syncthreads();
  if (tid < 32) {
    f32x4 s = red[0][tid];
    #pragma unroll
    for (int i = 1; i < 8; ++i) s += red[i][tid];
    s += *(const f32x4*)(bp + tid*4);
    *(f32x4*)(h0 + n*HH + tid*4) = s;
  }
}

// ---------------------------------------------------------------------------
// K_xb: xb[r][j] = b_ih[j]+b_hh[j] + sum_k embed[cap_in[r]][k]*W_ih[j][k]
// Thread = (row r, col-quad jq). All loads f32x4. 1024 blocks.
// ---------------------------------------------------------------------------
__global__ __launch_bounds__(256) void k_xb(const int* __restrict__ captions,
    const float* __restrict__ embed, const float* __restrict__ Wt,
    const float* __restrict__ bih, const float* __restrict__ bhh,
    float* __restrict__ xb) {
  int g = blockIdx.x*256 + threadIdx.x;   // 262144 threads
  int jq = (g & 31) * 4;
  int r  = g >> 5;                        // 0..8191
  int n = r >> 6, t = r & 63;
  const float* x = embed + (size_t)captions[n*65 + t] * WVD;
  f32x4 acc = *(const f32x4*)(bih + jq);
  acc += *(const f32x4*)(bhh + jq);
  #pragma unroll 4
  for (int k = 0; k < WVD; k += 4) {
    f32x4 xv = *(const f32x4*)(x + k);
    const float* wp = Wt + (size_t)k*HH + jq;
    f32x4 w0 = *(const f32x4*)(wp);
    f32x4 w1 = *(const f32x4*)(wp + HH);
    f32x4 w2 = *(const f32x4*)(wp + 2*HH);
    f32x4 w3 = *(const f32x4*)(wp + 3*HH);
    acc += xv[0]*w0;
    acc += xv[1]*w1;
    acc += xv[2]*w2;
    acc += xv[3]*w3;
  }
  *(f32x4*)(xb + (size_t)r*HH + jq) = acc;
}

// ---------------------------------------------------------------------------
// K_rnn: sequential RNN, one block (4 waves) per sample. LDS+VALU loop only.
// ---------------------------------------------------------------------------
__global__ __launch_bounds__(256) void k_rnn(const float* __restrict__ h0,
    const float* __restrict__ xb, const float* __restrict__ Whh,
    unsigned short* __restrict__ hsb) {
  __shared__ float xl[TT][HH];            // 32 KB
  __shared__ unsigned short hl[TT][HH];   // 16 KB
  __shared__ float hbuf[2][HH];           // 1 KB
  int n = blockIdx.x, tid = threadIdx.x;
  int w = tid >> 6, l = tid & 63;
  int j = w*32 + (l & 31);
  int kb = (l >> 5) * 64;

  const float* xsrc = xb + (size_t)n*TT*HH;
  #pragma unroll
  for (int it = 0; it < 8; ++it) {
    int o = it*256 + tid;
    *(f32x4*)(&xl[0][0] + o*4) = *(const f32x4*)(xsrc + o*4);
  }
  float wr_[64];
  const float* wsrc = Whh + (size_t)j*HH + kb;
  #pragma unroll
  for (int i = 0; i < 16; ++i) {
    f32x4 v = *(const f32x4*)(wsrc + i*4);
    wr_[i*4+0]=v[0]; wr_[i*4+1]=v[1]; wr_[i*4+2]=v[2]; wr_[i*4+3]=v[3];
  }
  if (tid < HH) hbuf[0][tid] = h0[n*HH + tid];
  __syncthreads();

  int cur = 0;
  for (int t = 0; t < TT; ++t) {
    float s0=0.f, s1=0.f, s2=0.f, s3=0.f;
    const float* hr = &hbuf[cur][kb];
    #pragma unroll
    for (int i = 0; i < 16; ++i) {
      f32x4 hv = *(const f32x4*)(hr + i*4);
      s0 += hv[0]*wr_[i*4+0]; s1 += hv[1]*wr_[i*4+1];
      s2 += hv[2]*wr_[i*4+2]; s3 += hv[3]*wr_[i*4+3];
    }
    float s = (s0+s1)+(s2+s3);
    s += __shfl_xor(s, 32);
    float v = s + xl[t][j];
    float e = __builtin_amdgcn_exp2f(v * (2.0f*LOG2E));
    float h = 1.0f - 2.0f*__builtin_amdgcn_rcpf(e + 1.0f);  // tanh
    if (l < 32) {
      hbuf[cur^1][j] = h;
      hl[t][j] = f2bf(h * LOG2E);
    }
    __syncthreads();
    cur ^= 1;
  }
  unsigned short* dst = hsb + (size_t)n*TT*HH;
  #pragma unroll
  for (int it = 0; it < 4; ++it) {
    int o = it*256 + tid;
    *(u32x4*)(dst + o*8) = *(const u32x4*)(&hl[0][0] + o*8);
  }
}

// ---------------------------------------------------------------------------
// K_loss: sum-exp of scores. Barrier-free, LDS-free, 2-deep SW pipeline.
// Grid = 32 row-blocks x 64 V-slices. Wave owns 64 rows (A-frags in regs).
// B-frags loaded global->reg one strip AHEAD of the MFMA+exp that uses them.
// ---------------------------------------------------------------------------
#define LOADB(dst, eb, sidx) do {                                            \
    const unsigned short* _p = wvt + (size_t)((sidx)*16 + lc)*HH + l4*8;     \
    dst[0] = *(const short8*)(_p);                                           \
    dst[1] = *(const short8*)(_p + 32);                                      \
    dst[2] = *(const short8*)(_p + 64);                                      \
    dst[3] = *(const short8*)(_p + 96);                                      \
    eb = expbv[(sidx)*16 + lc];                                              \
  } while(0)

#define COMPUTEB(bf, eb) do {                                                \
    _Pragma("unroll")                                                        \
    for (int sm = 0; sm < 4; ++sm) {                                         \
      f32x4 acc = {0.f,0.f,0.f,0.f};                                         \
      _Pragma("unroll")                                                      \
      for (int ks = 0; ks < 4; ++ks)                                         \
        acc = __builtin_amdgcn_mfma_f32_16x16x32_bf16(af[sm][ks], bf[ks], acc, 0, 0, 0); \
      _Pragma("unroll")                                                      \
      for (int jj = 0; jj < 4; ++jj)                                         \
        se[sm][jj] = fmaf(__builtin_amdgcn_exp2f(acc[jj]), eb, se[sm][jj]);  \
    }                                                                        \
  } while(0)

__global__ __launch_bounds__(256) void k_loss(
    const unsigned short* __restrict__ hsb,
    const unsigned short* __restrict__ wvt,
    const float* __restrict__ expbv,
    float* __restrict__ se_acc) {
  int tid = threadIdx.x;
  int w = tid >> 6, l = tid & 63;
  int l4 = l >> 4, lc = l & 15;
  int rb = blockIdx.x & 31;     // row-block: 256 rows
  int vb = blockIdx.x >> 5;     // V-slice
  int wrow = rb*256 + w*64;     // this wave's 64 rows

  short8 af[4][4];
  #pragma unroll
  for (int sm = 0; sm < 4; ++sm)
    #pragma unroll
    for (int ks = 0; ks < 4; ++ks)
      af[sm][ks] = *(const short8*)(hsb + (size_t)(wrow + sm*16 + lc)*HH + ks*32 + l4*8);

  float se[4][4] = {{0.f}};
  short8 bfA[4], bfB[4];
  float ebA = 0.f, ebB = 0.f;
  int s = vb;
  LOADB(bfA, ebA, s);
  for (;;) {
    int s1 = s + VSPLIT;
    if (s1 < NSTRIP) LOADB(bfB, ebB, s1);
    COMPUTEB(bfA, ebA);
    if (s1 >= NSTRIP) break;
    int s2 = s1 + VSPLIT;
    if (s2 < NSTRIP) LOADB(bfA, ebA, s2);
    COMPUTEB(bfB, ebB);
    if (s2 >= NSTRIP) break;
    s = s2;
  }

  #pragma unroll
  for (int sm = 0; sm < 4; ++sm)
    #pragma unroll
    for (int jj = 0; jj < 4; ++jj) {
      float v = se[sm][jj];
      v += __shfl_xor(v, 1); v += __shfl_xor(v, 2);
      v += __shfl_xor(v, 4); v += __shfl_xor(v, 8);
      se[sm][jj] = v;
    }
  if (lc == 0) {
    #pragma unroll
    for (int sm = 0; sm < 4; ++sm)
      #pragma unroll
      for (int jj = 0; jj < 4; ++jj)
        atomicAdd(&se_acc[wrow + sm*16 + l4*4 + jj], se[sm][jj]);
  }
}

// ---------------------------------------------------------------------------
// K_final: per-row target score + masked NLL reduction.
// ---------------------------------------------------------------------------
__global__ __launch_bounds__(256) void k_final(
    const unsigned short* __restrict__ hsb,
    const unsigned short* __restrict__ wvt,
    const float* __restrict__ bv,
    const float* __restrict__ se_acc,
    const int* __restrict__ captions,
    float* __restrict__ out) {
  int tid = threadIdx.x;
  int w = tid >> 6, l = tid & 63;
  int row = blockIdx.x*32 + w*8 + (l >> 3);
  int seg = l & 7;
  int n = row >> 6, t = row & 63;
  int tg = captions[n*65 + t + 1];
  float part = 0.f;
  if (tg != 0) {
    const unsigned short* a = hsb + (size_t)row*HH + seg*16;
    const unsigned short* b = wvt + (size_t)tg*HH + seg*16;
    short8 a0 = *(const short8*)a, a1 = *(const short8*)(a+8);
    short8 b0 = *(const short8*)b, b1 = *(const short8*)(b+8);
    #pragma unroll
    for (int i = 0; i < 8; ++i) {
      part += bf2f((unsigned short)a0[i]) * bf2f((unsigned short)b0[i]);
      part += bf2f((unsigned short)a1[i]) * bf2f((unsigned short)b1[i]);
    }
  }
  part += __shfl_xor(part, 1);
  part += __shfl_xor(part, 2);
  part += __shfl_xor(part, 4);
  if (seg == 0 && tg != 0) {
    float score = part * LN2 + bv[tg];
    float nll = logf(se_acc[row]) - score;
    atomicAdd(out, nll * (1.0f/128.0f));
  }
}

extern "C" void kernel_launch(void* const* d_in, const int* in_sizes, int n_in,
                              void* d_out, int out_size, void* d_ws, size_t ws_size,
                              hipStream_t stream) {
  const float* features = (const float*)d_in[0];
  const int*   captions = (const int*)d_in[1];
  const float* W_proj   = (const float*)d_in[2];
  const float* b_proj   = (const float*)d_in[3];
  const float* embed    = (const float*)d_in[4];
  const float* W_ih     = (const float*)d_in[5];
  const float* W_hh     = (const float*)d_in[6];
  const float* b_ih     = (const float*)d_in[7];
  const float* b_hh     = (const float*)d_in[8];
  const float* W_vocab  = (const float*)d_in[9];
  const float* b_vocab  = (const float*)d_in[10];
  float* out = (float*)d_out;
  char* ws = (char*)d_ws;

  float*          h0     = (float*)(ws + 0x000000);            // 64 KB
  float*          xb     = (float*)(ws + 0x010000);            // 4 MB
  unsigned short* hsb    = (unsigned short*)(ws + 0x410000);   // 2 MB
  float*          wih_t  = (float*)(ws + 0x610000);            // 64 KB
  unsigned short* wvt    = (unsigned short*)(ws + 0x620000);   // 2.57 MB
  float*          expbv  = (float*)(ws + 0x8A0000);            // 40 KB
  float*          se_acc = (float*)(ws + 0x8B0000);            // 32 KB

  hipLaunchKernelGGL(k_prep, dim3(427), dim3(256), 0, stream,
                     W_vocab, wvt, W_ih, wih_t, b_vocab, expbv, se_acc, out);
  hipLaunchKernelGGL(k_h0,   dim3(NB), dim3(256), 0, stream, features, W_proj, b_proj, h0);
  hipLaunchKernelGGL(k_xb,   dim3(NROW*32/256), dim3(256), 0, stream, captions, embed, wih_t, b_ih, b_hh, xb);
  hipLaunchKernelGGL(k_rnn,  dim3(NB), dim3(256), 0, stream, h0, xb, W_hh, hsb);
  hipLaunchKernelGGL(k_loss, dim3(32*VSPLIT), dim3(256), 0, stream, hsb, wvt, expbv, se_acc);
  hipLaunchKernelGGL(k_final, dim3(NROW/32), dim3(256), 0, stream, hsb, wvt, b_vocab, se_acc, captions, out);
}

// Round 6
// 139.320 us; speedup vs baseline: 2.3761x; 1.0054x over previous
//
#include <hip/hip_runtime.h>
#include <hip/hip_bf16.h>
#include <math.h>

typedef __attribute__((ext_vector_type(8))) short short8;
typedef __attribute__((ext_vector_type(4))) float f32x4;
typedef __attribute__((ext_vector_type(4))) unsigned int u32x4;

#define NB   128   // batch
#define TT   64    // timesteps (T-1)
#define DD   512   // feature dim
#define HH   128   // hidden dim
#define WVD  128   // wordvec dim
#define VV   10000 // vocab
#define VP   10048 // vocab padded to multiple of 64
#define NROW (NB*TT)
#define NSTRIP (VP/16)   // 628 column strips of 16
#define VSPLIT 64        // V-slices per row-block
#define LOG2E 1.44269504088896f
#define LN2   0.69314718055995f

__device__ __forceinline__ unsigned short f2bf(float x) {
  union { float f; unsigned int u; } v; v.f = x;
  unsigned int r = v.u + 0x7fffu + ((v.u >> 16) & 1u);
  return (unsigned short)(r >> 16);
}
__device__ __forceinline__ float bf2f(unsigned short u) {
  union { unsigned int i; float f; } v; v.i = ((unsigned int)u) << 16; return v.f;
}

// ---------------------------------------------------------------------------
// K_prep: fused prep. Blocks:
//   [0,314)    : Wvt[v][k] = bf16(W_vocab[k][v])  (64x64 LDS tile transpose)
//   [314,378)  : Wt[k*128+j] = W_ih[j][k]
//   [378,418)  : expbv[v] = exp(b_vocab[v]) (0 for pad)
//   [418,426)  : se_acc = 0
//   426        : out = 0
// ---------------------------------------------------------------------------
__global__ __launch_bounds__(256) void k_prep(
    const float* __restrict__ Wv, unsigned short* __restrict__ Wvt,
    const float* __restrict__ Wih, float* __restrict__ Wt,
    const float* __restrict__ bv, float* __restrict__ expbv,
    float* __restrict__ se_acc, float* __restrict__ out) {
  __shared__ float tile[64][65];
  int b = blockIdx.x, tid = threadIdx.x;
  if (b < 314) {
    int bvv = (b >> 1) * 64;            // v tile base
    int bk  = (b & 1) * 64;             // k tile base
    int tv = tid & 63;
    int tk0 = tid >> 6;                 // 0..3
    #pragma unroll
    for (int kk = 0; kk < 64; kk += 4) {
      int k = bk + kk + tk0;
      int v = bvv + tv;
      tile[kk + tk0][tv] = (v < VV) ? Wv[(size_t)k*VV + v] : 0.f;
    }
    __syncthreads();
    int tk = tid & 63;
    int tv0 = tid >> 6;
    #pragma unroll
    for (int vv = 0; vv < 64; vv += 4) {
      int v = bvv + vv + tv0;
      Wvt[(size_t)v*HH + bk + tk] = f2bf(tile[tk][vv + tv0]);
    }
  } else if (b < 378) {
    int o = (b - 314)*256 + tid;
    int k = o >> 7, j = o & 127;
    Wt[o] = Wih[j*WVD + k];
  } else if (b < 418) {
    int v = (b - 378)*256 + tid;
    if (v < VP) expbv[v] = (v < VV) ? __expf(bv[v]) : 0.f;
  } else if (b < 426) {
    int idx = (b - 418)*1024 + tid*4;
    f32x4 z = {0.f,0.f,0.f,0.f};
    *(f32x4*)(se_acc + idx) = z;
  } else {
    if (tid == 0) out[0] = 0.f;
  }
}

// ---------------------------------------------------------------------------
// K_h0: h0 = features @ W_proj + b_proj. One block (256 thr) per sample.
// Thread = (jq = 4-col quad, ks = 64-k slice); f32x4 loads; LDS reduce.
// ---------------------------------------------------------------------------
__global__ __launch_bounds__(256) void k_h0(const float* __restrict__ features,
    const float* __restrict__ Wp, const float* __restrict__ bp,
    float* __restrict__ h0) {
  __shared__ float fl[DD];
  __shared__ f32x4 red[8][32];
  int n = blockIdx.x, tid = threadIdx.x;
  fl[tid]       = features[n*DD + tid];
  fl[tid + 256] = features[n*DD + 256 + tid];
  __syncthreads();
  int jq = (tid & 31) * 4;
  int ks = tid >> 5;                    // 0..7
  f32x4 acc = {0.f,0.f,0.f,0.f};
  const float* wp = Wp + (size_t)(ks*64)*HH + jq;
  #pragma unroll 4
  for (int k = 0; k < 64; ++k) {
    f32x4 wv = *(const f32x4*)(wp + (size_t)k*HH);
    acc += fl[ks*64 + k] * wv;
  }
  red[ks][tid & 31] = acc;
  __syncthreads();
  if (tid < 32) {
    f32x4 s = red[0][tid];
    #pragma unroll
    for (int i = 1; i < 8; ++i) s += red[i][tid];
    s += *(const f32x4*)(bp + tid*4);
    *(f32x4*)(h0 + n*HH + tid*4) = s;
  }
}

// ---------------------------------------------------------------------------
// K_xb: xb[r][j] = b_ih[j]+b_hh[j] + sum_k embed[cap_in[r]][k]*W_ih[j][k]
// Thread = (row r, col-quad jq). All loads f32x4. 1024 blocks.
// ---------------------------------------------------------------------------
__global__ __launch_bounds__(256) void k_xb(const int* __restrict__ captions,
    const float* __restrict__ embed, const float* __restrict__ Wt,
    const float* __restrict__ bih, const float* __restrict__ bhh,
    float* __restrict__ xb) {
  int g = blockIdx.x*256 + threadIdx.x;   // 262144 threads
  int jq = (g & 31) * 4;
  int r  = g >> 5;                        // 0..8191
  int n = r >> 6, t = r & 63;
  const float* x = embed + (size_t)captions[n*65 + t] * WVD;
  f32x4 acc = *(const f32x4*)(bih + jq);
  acc += *(const f32x4*)(bhh + jq);
  #pragma unroll 4
  for (int k = 0; k < WVD; k += 4) {
    f32x4 xv = *(const f32x4*)(x + k);
    const float* wp = Wt + (size_t)k*HH + jq;
    f32x4 w0 = *(const f32x4*)(wp);
    f32x4 w1 = *(const f32x4*)(wp + HH);
    f32x4 w2 = *(const f32x4*)(wp + 2*HH);
    f32x4 w3 = *(const f32x4*)(wp + 3*HH);
    acc += xv[0]*w0;
    acc += xv[1]*w1;
    acc += xv[2]*w2;
    acc += xv[3]*w3;
  }
  *(f32x4*)(xb + (size_t)r*HH + jq) = acc;
}

// ---------------------------------------------------------------------------
// K_rnn: sequential RNN, one block (4 waves) per sample. LDS+VALU loop only.
// ---------------------------------------------------------------------------
__global__ __launch_bounds__(256) void k_rnn(const float* __restrict__ h0,
    const float* __restrict__ xb, const float* __restrict__ Whh,
    unsigned short* __restrict__ hsb) {
  __shared__ float xl[TT][HH];            // 32 KB
  __shared__ unsigned short hl[TT][HH];   // 16 KB
  __shared__ float hbuf[2][HH];           // 1 KB
  int n = blockIdx.x, tid = threadIdx.x;
  int w = tid >> 6, l = tid & 63;
  int j = w*32 + (l & 31);
  int kb = (l >> 5) * 64;

  const float* xsrc = xb + (size_t)n*TT*HH;
  #pragma unroll
  for (int it = 0; it < 8; ++it) {
    int o = it*256 + tid;
    *(f32x4*)(&xl[0][0] + o*4) = *(const f32x4*)(xsrc + o*4);
  }
  float wr_[64];
  const float* wsrc = Whh + (size_t)j*HH + kb;
  #pragma unroll
  for (int i = 0; i < 16; ++i) {
    f32x4 v = *(const f32x4*)(wsrc + i*4);
    wr_[i*4+0]=v[0]; wr_[i*4+1]=v[1]; wr_[i*4+2]=v[2]; wr_[i*4+3]=v[3];
  }
  if (tid < HH) hbuf[0][tid] = h0[n*HH + tid];
  __syncthreads();

  int cur = 0;
  for (int t = 0; t < TT; ++t) {
    float s0=0.f, s1=0.f, s2=0.f, s3=0.f;
    const float* hr = &hbuf[cur][kb];
    #pragma unroll
    for (int i = 0; i < 16; ++i) {
      f32x4 hv = *(const f32x4*)(hr + i*4);
      s0 += hv[0]*wr_[i*4+0]; s1 += hv[1]*wr_[i*4+1];
      s2 += hv[2]*wr_[i*4+2]; s3 += hv[3]*wr_[i*4+3];
    }
    float s = (s0+s1)+(s2+s3);
    s += __shfl_xor(s, 32);
    float v = s + xl[t][j];
    float e = __builtin_amdgcn_exp2f(v * (2.0f*LOG2E));
    float h = 1.0f - 2.0f*__builtin_amdgcn_rcpf(e + 1.0f);  // tanh
    if (l < 32) {
      hbuf[cur^1][j] = h;
      hl[t][j] = f2bf(h * LOG2E);
    }
    __syncthreads();
    cur ^= 1;
  }
  unsigned short* dst = hsb + (size_t)n*TT*HH;
  #pragma unroll
  for (int it = 0; it < 4; ++it) {
    int o = it*256 + tid;
    *(u32x4*)(dst + o*8) = *(const u32x4*)(&hl[0][0] + o*8);
  }
}

// ---------------------------------------------------------------------------
// K_loss: sum-exp of scores. Barrier-free, LDS-free, 2-deep SW pipeline.
// Grid = 32 row-blocks x 64 V-slices. Wave owns 64 rows (A-frags in regs).
// B-frags loaded global->reg one strip AHEAD of the MFMA+exp that uses them.
// ---------------------------------------------------------------------------
#define LOADB(dst, eb, sidx) do {                                            \
    const unsigned short* _p = wvt + (size_t)((sidx)*16 + lc)*HH + l4*8;     \
    dst[0] = *(const short8*)(_p);                                           \
    dst[1] = *(const short8*)(_p + 32);                                      \
    dst[2] = *(const short8*)(_p + 64);                                      \
    dst[3] = *(const short8*)(_p + 96);                                      \
    eb = expbv[(sidx)*16 + lc];                                              \
  } while(0)

#define COMPUTEB(bf, eb) do {                                                \
    _Pragma("unroll")                                                        \
    for (int sm = 0; sm < 4; ++sm) {                                         \
      f32x4 acc = {0.f,0.f,0.f,0.f};                                         \
      _Pragma("unroll")                                                      \
      for (int ks = 0; ks < 4; ++ks)                                         \
        acc = __builtin_amdgcn_mfma_f32_16x16x32_bf16(af[sm][ks], bf[ks], acc, 0, 0, 0); \
      _Pragma("unroll")                                                      \
      for (int jj = 0; jj < 4; ++jj)                                         \
        se[sm][jj] = fmaf(__builtin_amdgcn_exp2f(acc[jj]), eb, se[sm][jj]);  \
    }                                                                        \
  } while(0)

__global__ __launch_bounds__(256) void k_loss(
    const unsigned short* __restrict__ hsb,
    const unsigned short* __restrict__ wvt,
    const float* __restrict__ expbv,
    float* __restrict__ se_acc) {
  int tid = threadIdx.x;
  int w = tid >> 6, l = tid & 63;
  int l4 = l >> 4, lc = l & 15;
  int rb = blockIdx.x & 31;     // row-block: 256 rows
  int vb = blockIdx.x >> 5;     // V-slice
  int wrow = rb*256 + w*64;     // this wave's 64 rows

  short8 af[4][4];
  #pragma unroll
  for (int sm = 0; sm < 4; ++sm)
    #pragma unroll
    for (int ks = 0; ks < 4; ++ks)
      af[sm][ks] = *(const short8*)(hsb + (size_t)(wrow + sm*16 + lc)*HH + ks*32 + l4*8);

  float se[4][4] = {{0.f}};
  short8 bfA[4], bfB[4];
  float ebA = 0.f, ebB = 0.f;
  int s = vb;
  LOADB(bfA, ebA, s);
  for (;;) {
    int s1 = s + VSPLIT;
    if (s1 < NSTRIP) LOADB(bfB, ebB, s1);
    COMPUTEB(bfA, ebA);
    if (s1 >= NSTRIP) break;
    int s2 = s1 + VSPLIT;
    if (s2 < NSTRIP) LOADB(bfA, ebA, s2);
    COMPUTEB(bfB, ebB);
    if (s2 >= NSTRIP) break;
    s = s2;
  }

  #pragma unroll
  for (int sm = 0; sm < 4; ++sm)
    #pragma unroll
    for (int jj = 0; jj < 4; ++jj) {
      float v = se[sm][jj];
      v += __shfl_xor(v, 1); v += __shfl_xor(v, 2);
      v += __shfl_xor(v, 4); v += __shfl_xor(v, 8);
      se[sm][jj] = v;
    }
  if (lc == 0) {
    #pragma unroll
    for (int sm = 0; sm < 4; ++sm)
      #pragma unroll
      for (int jj = 0; jj < 4; ++jj)
        atomicAdd(&se_acc[wrow + sm*16 + l4*4 + jj], se[sm][jj]);
  }
}

// ---------------------------------------------------------------------------
// K_final: per-row target score + masked NLL reduction.
// ---------------------------------------------------------------------------
__global__ __launch_bounds__(256) void k_final(
    const unsigned short* __restrict__ hsb,
    const unsigned short* __restrict__ wvt,
    const float* __restrict__ bv,
    const float* __restrict__ se_acc,
    const int* __restrict__ captions,
    float* __restrict__ out) {
  int tid = threadIdx.x;
  int w = tid >> 6, l = tid & 63;
  int row = blockIdx.x*32 + w*8 + (l >> 3);
  int seg = l & 7;
  int n = row >> 6, t = row & 63;
  int tg = captions[n*65 + t + 1];
  float part = 0.f;
  if (tg != 0) {
    const unsigned short* a = hsb + (size_t)row*HH + seg*16;
    const unsigned short* b = wvt + (size_t)tg*HH + seg*16;
    short8 a0 = *(const short8*)a, a1 = *(const short8*)(a+8);
    short8 b0 = *(const short8*)b, b1 = *(const short8*)(b+8);
    #pragma unroll
    for (int i = 0; i < 8; ++i) {
      part += bf2f((unsigned short)a0[i]) * bf2f((unsigned short)b0[i]);
      part += bf2f((unsigned short)a1[i]) * bf2f((unsigned short)b1[i]);
    }
  }
  part += __shfl_xor(part, 1);
  part += __shfl_xor(part, 2);
  part += __shfl_xor(part, 4);
  if (seg == 0 && tg != 0) {
    float score = part * LN2 + bv[tg];
    float nll = logf(se_acc[row]) - score;
    atomicAdd(out, nll * (1.0f/128.0f));
  }
}

extern "C" void kernel_launch(void* const* d_in, const int* in_sizes, int n_in,
                              void* d_out, int out_size, void* d_ws, size_t ws_size,
                              hipStream_t stream) {
  const float* features = (const float*)d_in[0];
  const int*   captions = (const int*)d_in[1];
  const float* W_proj   = (const float*)d_in[2];
  const float* b_proj   = (const float*)d_in[3];
  const float* embed    = (const float*)d_in[4];
  const float* W_ih     = (const float*)d_in[5];
  const float* W_hh     = (const float*)d_in[6];
  const float* b_ih     = (const float*)d_in[7];
  const float* b_hh     = (const float*)d_in[8];
  const float* W_vocab  = (const float*)d_in[9];
  const float* b_vocab  = (const float*)d_in[10];
  float* out = (float*)d_out;
  char* ws = (char*)d_ws;

  float*          h0     = (float*)(ws + 0x000000);            // 64 KB
  float*          xb     = (float*)(ws + 0x010000);            // 4 MB
  unsigned short* hsb    = (unsigned short*)(ws + 0x410000);   // 2 MB
  float*          wih_t  = (float*)(ws + 0x610000);            // 64 KB
  unsigned short* wvt    = (unsigned short*)(ws + 0x620000);   // 2.57 MB
  float*          expbv  = (float*)(ws + 0x8A0000);            // 40 KB
  float*          se_acc = (float*)(ws + 0x8B0000);            // 32 KB

  hipLaunchKernelGGL(k_prep, dim3(427), dim3(256), 0, stream,
                     W_vocab, wvt, W_ih, wih_t, b_vocab, expbv, se_acc, out);
  hipLaunchKernelGGL(k_h0,   dim3(NB), dim3(256), 0, stream, features, W_proj, b_proj, h0);
  hipLaunchKernelGGL(k_xb,   dim3(NROW*32/256), dim3(256), 0, stream, captions, embed, wih_t, b_ih, b_hh, xb);
  hipLaunchKernelGGL(k_rnn,  dim3(NB), dim3(256), 0, stream, h0, xb, W_hh, hsb);
  hipLaunchKernelGGL(k_loss, dim3(32*VSPLIT), dim3(256), 0, stream, hsb, wvt, expbv, se_acc);
  hipLaunchKernelGGL(k_final, dim3(NROW/32), dim3(256), 0, stream, hsb, wvt, b_vocab, se_acc, captions, out);
}

// Round 7
// 111.373 us; speedup vs baseline: 2.9724x; 1.2509x over previous
//
#include <hip/hip_runtime.h>
#include <hip/hip_bf16.h>
#include <math.h>

typedef __attribute__((ext_vector_type(8))) short short8;
typedef __attribute__((ext_vector_type(4))) float f32x4;
typedef __attribute__((ext_vector_type(4))) unsigned int u32x4;

#define NB   128   // batch
#define TT   64    // timesteps (T-1)
#define DD   512   // feature dim
#define HH   128   // hidden dim
#define WVD  128   // wordvec dim
#define VV   10000 // vocab
#define VP   10048 // vocab padded to multiple of 64
#define NROW (NB*TT)
#define NTILE (VP/64)    // 157 column tiles of 64
#define VT   32          // col-tile streams (blocks per row-block)
#define TILE_BYTES 16384 // 64 cols x 128 k x 2 B
#define LOG2E 1.44269504088896f
#define LN2   0.69314718055995f

__device__ __forceinline__ unsigned short f2bf(float x) {
  union { float f; unsigned int u; } v; v.f = x;
  unsigned int r = v.u + 0x7fffu + ((v.u >> 16) & 1u);
  return (unsigned short)(r >> 16);
}
__device__ __forceinline__ float bf2f(unsigned short u) {
  union { unsigned int i; float f; } v; v.i = ((unsigned int)u) << 16; return v.f;
}

// ---------------------------------------------------------------------------
// K_prep: fused prep + h0. Blocks:
//   [0,314)    : Wvt[v][k] = bf16(W_vocab[k][v])  (64x64 LDS tile transpose)
//   [314,378)  : Wt[k*128+j] = W_ih[j][k]
//   [378,418)  : expbv[v] = exp(b_vocab[v]) (0 for pad)
//   418        : out = 0
//   [419,547)  : h0[n] = features[n] @ W_proj + b_proj,  n = b-419
// ---------------------------------------------------------------------------
__global__ __launch_bounds__(256) void k_prep(
    const float* __restrict__ Wv, unsigned short* __restrict__ Wvt,
    const float* __restrict__ Wih, float* __restrict__ Wt,
    const float* __restrict__ bv, float* __restrict__ expbv,
    float* __restrict__ out,
    const float* __restrict__ features, const float* __restrict__ Wp,
    const float* __restrict__ bp, float* __restrict__ h0) {
  __shared__ float tile[64][65];
  int b = blockIdx.x, tid = threadIdx.x;
  if (b < 314) {
    int bvv = (b >> 1) * 64;            // v tile base
    int bk  = (b & 1) * 64;             // k tile base
    int tv = tid & 63;
    int tk0 = tid >> 6;                 // 0..3
    #pragma unroll
    for (int kk = 0; kk < 64; kk += 4) {
      int k = bk + kk + tk0;
      int v = bvv + tv;
      tile[kk + tk0][tv] = (v < VV) ? Wv[(size_t)k*VV + v] : 0.f;
    }
    __syncthreads();
    int tk = tid & 63;
    int tv0 = tid >> 6;
    #pragma unroll
    for (int vv = 0; vv < 64; vv += 4) {
      int v = bvv + vv + tv0;
      Wvt[(size_t)v*HH + bk + tk] = f2bf(tile[tk][vv + tv0]);
    }
  } else if (b < 378) {
    int o = (b - 314)*256 + tid;
    int k = o >> 7, j = o & 127;
    Wt[o] = Wih[j*WVD + k];
  } else if (b < 418) {
    int v = (b - 378)*256 + tid;
    if (v < VP) expbv[v] = (v < VV) ? __expf(bv[v]) : 0.f;
  } else if (b == 418) {
    if (tid == 0) out[0] = 0.f;
  } else {
    // h0 for sample n
    int n = b - 419;
    float* fl  = &tile[0][0];                 // 512 floats (2 KB)
    f32x4* red = (f32x4*)&tile[20][0];        // 256 f32x4 (4 KB), 16B-aligned
    fl[tid]       = features[n*DD + tid];
    fl[tid + 256] = features[n*DD + 256 + tid];
    __syncthreads();
    int jq = (tid & 31) * 4;
    int ks = tid >> 5;                        // 0..7
    f32x4 acc = {0.f,0.f,0.f,0.f};
    const float* wp = Wp + (size_t)(ks*64)*HH + jq;
    #pragma unroll 4
    for (int k = 0; k < 64; ++k) {
      f32x4 wv = *(const f32x4*)(wp + (size_t)k*HH);
      acc += fl[ks*64 + k] * wv;
    }
    red[ks*32 + (tid & 31)] = acc;
    __syncthreads();
    if (tid < 32) {
      f32x4 s = red[tid];
      #pragma unroll
      for (int i = 1; i < 8; ++i) s += red[i*32 + tid];
      s += *(const f32x4*)(bp + tid*4);
      *(f32x4*)(h0 + n*HH + tid*4) = s;
    }
  }
}

// ---------------------------------------------------------------------------
// K_xb: xb[r][j] = b_ih[j]+b_hh[j] + sum_k embed[cap_in[r]][k]*W_ih[j][k]
// ---------------------------------------------------------------------------
__global__ __launch_bounds__(256) void k_xb(const int* __restrict__ captions,
    const float* __restrict__ embed, const float* __restrict__ Wt,
    const float* __restrict__ bih, const float* __restrict__ bhh,
    float* __restrict__ xb) {
  int g = blockIdx.x*256 + threadIdx.x;   // 262144 threads
  int jq = (g & 31) * 4;
  int r  = g >> 5;                        // 0..8191
  int n = r >> 6, t = r & 63;
  const float* x = embed + (size_t)captions[n*65 + t] * WVD;
  f32x4 acc = *(const f32x4*)(bih + jq);
  acc += *(const f32x4*)(bhh + jq);
  #pragma unroll 4
  for (int k = 0; k < WVD; k += 4) {
    f32x4 xv = *(const f32x4*)(x + k);
    const float* wp = Wt + (size_t)k*HH + jq;
    f32x4 w0 = *(const f32x4*)(wp);
    f32x4 w1 = *(const f32x4*)(wp + HH);
    f32x4 w2 = *(const f32x4*)(wp + 2*HH);
    f32x4 w3 = *(const f32x4*)(wp + 3*HH);
    acc += xv[0]*w0;
    acc += xv[1]*w1;
    acc += xv[2]*w2;
    acc += xv[3]*w3;
  }
  *(f32x4*)(xb + (size_t)r*HH + jq) = acc;
}

// ---------------------------------------------------------------------------
// K_rnn: sequential RNN, one block (4 waves) per sample. LDS+VALU loop only.
// ---------------------------------------------------------------------------
__global__ __launch_bounds__(256) void k_rnn(const float* __restrict__ h0,
    const float* __restrict__ xb, const float* __restrict__ Whh,
    unsigned short* __restrict__ hsb) {
  __shared__ float xl[TT][HH];            // 32 KB
  __shared__ unsigned short hl[TT][HH];   // 16 KB
  __shared__ float hbuf[2][HH];           // 1 KB
  int n = blockIdx.x, tid = threadIdx.x;
  int w = tid >> 6, l = tid & 63;
  int j = w*32 + (l & 31);
  int kb = (l >> 5) * 64;

  const float* xsrc = xb + (size_t)n*TT*HH;
  #pragma unroll
  for (int it = 0; it < 8; ++it) {
    int o = it*256 + tid;
    *(f32x4*)(&xl[0][0] + o*4) = *(const f32x4*)(xsrc + o*4);
  }
  float wr_[64];
  const float* wsrc = Whh + (size_t)j*HH + kb;
  #pragma unroll
  for (int i = 0; i < 16; ++i) {
    f32x4 v = *(const f32x4*)(wsrc + i*4);
    wr_[i*4+0]=v[0]; wr_[i*4+1]=v[1]; wr_[i*4+2]=v[2]; wr_[i*4+3]=v[3];
  }
  if (tid < HH) hbuf[0][tid] = h0[n*HH + tid];
  __syncthreads();

  int cur = 0;
  for (int t = 0; t < TT; ++t) {
    float s0=0.f, s1=0.f, s2=0.f, s3=0.f;
    const float* hr = &hbuf[cur][kb];
    #pragma unroll
    for (int i = 0; i < 16; ++i) {
      f32x4 hv = *(const f32x4*)(hr + i*4);
      s0 += hv[0]*wr_[i*4+0]; s1 += hv[1]*wr_[i*4+1];
      s2 += hv[2]*wr_[i*4+2]; s3 += hv[3]*wr_[i*4+3];
    }
    float s = (s0+s1)+(s2+s3);
    s += __shfl_xor(s, 32);
    float v = s + xl[t][j];
    float e = __builtin_amdgcn_exp2f(v * (2.0f*LOG2E));
    float h = 1.0f - 2.0f*__builtin_amdgcn_rcpf(e + 1.0f);  // tanh
    if (l < 32) {
      hbuf[cur^1][j] = h;
      hl[t][j] = f2bf(h * LOG2E);
    }
    __syncthreads();
    cur ^= 1;
  }
  unsigned short* dst = hsb + (size_t)n*TT*HH;
  #pragma unroll
  for (int it = 0; it < 4; ++it) {
    int o = it*256 + tid;
    *(u32x4*)(dst + o*8) = *(const u32x4*)(&hl[0][0] + o*8);
  }
}

// ---------------------------------------------------------------------------
// K_loss v3: sum-exp of scores via LDS-staged B, 2-phase pipeline.
// Grid = rb(32 row-blocks) x vt(32 col streams), blockIdx = rb*32+vt so all
// 32 blocks sharing a tile stream land on one XCD (wgid%8 = vt%8).
// Tile = 64 cols (16 KB bf16), double-buffered via global_load_lds width=16.
// XOR-swizzle (off ^= (col&7)<<4) applied on the pre-swizzled GLOBAL source
// (linear LDS dest) and on the ds_read address -> conflict-free b128 reads.
// Per tile per wave: 16 ds_read_b128 + 64 MFMA + 64 exp2+fma (~1.5K cyc)
// between barriers -> staging latency fully hidden.
// Output: per-(vt,row) partial sums, NO atomics.
// ---------------------------------------------------------------------------
__global__ __launch_bounds__(256) void k_loss(
    const unsigned short* __restrict__ hsb,
    const unsigned short* __restrict__ wvt,
    const float* __restrict__ expbv,
    float* __restrict__ se_part) {
  __shared__ unsigned short bt[2][TILE_BYTES/2];   // 2 x 16 KB
  int tid = threadIdx.x;
  int w = tid >> 6, l = tid & 63;
  int l4 = l >> 4, lc = l & 15;
  int rb = blockIdx.x >> 5;
  int vt = blockIdx.x & 31;
  int wrow = rb*256 + w*64;

  // A fragments: 64 rows per wave, held in 64 VGPRs
  short8 af[4][4];
  #pragma unroll
  for (int sm = 0; sm < 4; ++sm)
    #pragma unroll
    for (int ks = 0; ks < 4; ++ks)
      af[sm][ks] = *(const short8*)(hsb + (size_t)(wrow + sm*16 + lc)*HH + ks*32 + l4*8);

  // swizzled ds_read sub-offsets (lane-constant)
  int T = (lc & 7) << 4;
  int sb[4];
  #pragma unroll
  for (int ks = 0; ks < 4; ++ks) sb[ks] = ((ks*64) + l4*16) ^ T;

#define STAGE(bufi, ct) do {                                                  \
    const char* _gb = (const char*)wvt + (size_t)(ct)*TILE_BYTES;             \
    _Pragma("unroll")                                                         \
    for (int q = 0; q < 4; ++q) {                                             \
      int _off = w*4096 + q*1024 + l*16;                                      \
      int _src = _off ^ (((_off >> 8) & 7) << 4);                             \
      __builtin_amdgcn_global_load_lds(                                       \
        (const __attribute__((address_space(1))) void*)(_gb + _src),          \
        (__attribute__((address_space(3))) void*)((char*)&bt[bufi][0] + w*4096 + q*1024), \
        16, 0, 0);                                                            \
    }                                                                         \
  } while (0)

#define EBLOAD(dst, ct) do {                                                  \
    const float* _e = expbv + (ct)*64 + lc;                                   \
    dst[0] = _e[0]; dst[1] = _e[16]; dst[2] = _e[32]; dst[3] = _e[48];        \
  } while (0)

#define COMPUTE(bufi, ebv_) do {                                              \
    const char* _Bb = (const char*)&bt[bufi][0];                              \
    _Pragma("unroll")                                                         \
    for (int st = 0; st < 4; ++st) {                                          \
      const char* _Bs = _Bb + st*4096 + lc*256;                               \
      short8 _b0 = *(const short8*)(_Bs + sb[0]);                             \
      short8 _b1 = *(const short8*)(_Bs + sb[1]);                             \
      short8 _b2 = *(const short8*)(_Bs + sb[2]);                             \
      short8 _b3 = *(const short8*)(_Bs + sb[3]);                             \
      float _eb = ebv_[st];                                                   \
      _Pragma("unroll")                                                       \
      for (int sm = 0; sm < 4; ++sm) {                                        \
        f32x4 _acc = {0.f,0.f,0.f,0.f};                                       \
        _acc = __builtin_amdgcn_mfma_f32_16x16x32_bf16(af[sm][0], _b0, _acc, 0,0,0); \
        _acc = __builtin_amdgcn_mfma_f32_16x16x32_bf16(af[sm][1], _b1, _acc, 0,0,0); \
        _acc = __builtin_amdgcn_mfma_f32_16x16x32_bf16(af[sm][2], _b2, _acc, 0,0,0); \
        _acc = __builtin_amdgcn_mfma_f32_16x16x32_bf16(af[sm][3], _b3, _acc, 0,0,0); \
        _Pragma("unroll")                                                     \
        for (int jj = 0; jj < 4; ++jj)                                        \
          se[sm][jj] = fmaf(__builtin_amdgcn_exp2f(_acc[jj]), _eb, se[sm][jj]); \
      }                                                                       \
    }                                                                         \
  } while (0)

  float se[4][4] = {{0.f}};
  float ebc[4], ebn[4];
  STAGE(0, vt);
  EBLOAD(ebc, vt);
  __syncthreads();                        // drains vmcnt(0): buf0 ready
  int i = 0;
  for (;;) {
    int nextct = vt + (i+1)*VT;
    if (nextct < NTILE) { STAGE((i+1)&1, nextct); EBLOAD(ebn, nextct); }
    COMPUTE(i&1, ebc);
    if (nextct >= NTILE) break;
    __syncthreads();                      // next buf staged + all reads done
    ebc[0]=ebn[0]; ebc[1]=ebn[1]; ebc[2]=ebn[2]; ebc[3]=ebn[3];
    ++i;
  }

  // reduce over cols (lc) within each 16-lane group
  #pragma unroll
  for (int sm = 0; sm < 4; ++sm)
    #pragma unroll
    for (int jj = 0; jj < 4; ++jj) {
      float v = se[sm][jj];
      v += __shfl_xor(v, 1); v += __shfl_xor(v, 2);
      v += __shfl_xor(v, 4); v += __shfl_xor(v, 8);
      se[sm][jj] = v;
    }
  if (lc == 0) {
    #pragma unroll
    for (int sm = 0; sm < 4; ++sm)
      #pragma unroll
      for (int jj = 0; jj < 4; ++jj)
        se_part[(size_t)vt*NROW + wrow + sm*16 + l4*4 + jj] = se[sm][jj];
  }
#undef STAGE
#undef EBLOAD
#undef COMPUTE
}

// ---------------------------------------------------------------------------
// K_final: sum 32 partials per row + target score + masked NLL reduction.
// ---------------------------------------------------------------------------
__global__ __launch_bounds__(256) void k_final(
    const unsigned short* __restrict__ hsb,
    const unsigned short* __restrict__ wvt,
    const float* __restrict__ bv,
    const float* __restrict__ se_part,
    const int* __restrict__ captions,
    float* __restrict__ out) {
  int tid = threadIdx.x;
  int w = tid >> 6, l = tid & 63;
  int row = blockIdx.x*32 + w*8 + (l >> 3);
  int seg = l & 7;
  int n = row >> 6, t = row & 63;
  int tg = captions[n*65 + t + 1];
  // partial sum-exp: each seg lane sums 4 of the 32 slabs
  float sep = 0.f;
  #pragma unroll
  for (int i = 0; i < 4; ++i)
    sep += se_part[(size_t)(seg*4 + i)*NROW + row];
  // target-score dot (only for unmasked rows)
  float part = 0.f;
  if (tg != 0) {
    const unsigned short* a = hsb + (size_t)row*HH + seg*16;
    const unsigned short* b = wvt + (size_t)tg*HH + seg*16;
    short8 a0 = *(const short8*)a, a1 = *(const short8*)(a+8);
    short8 b0 = *(const short8*)b, b1 = *(const short8*)(b+8);
    #pragma unroll
    for (int i = 0; i < 8; ++i) {
      part += bf2f((unsigned short)a0[i]) * bf2f((unsigned short)b0[i]);
      part += bf2f((unsigned short)a1[i]) * bf2f((unsigned short)b1[i]);
    }
  }
  part += __shfl_xor(part, 1); sep += __shfl_xor(sep, 1);
  part += __shfl_xor(part, 2); sep += __shfl_xor(sep, 2);
  part += __shfl_xor(part, 4); sep += __shfl_xor(sep, 4);
  if (seg == 0 && tg != 0) {
    float score = part * LN2 + bv[tg];
    float nll = logf(sep) - score;
    atomicAdd(out, nll * (1.0f/128.0f));
  }
}

extern "C" void kernel_launch(void* const* d_in, const int* in_sizes, int n_in,
                              void* d_out, int out_size, void* d_ws, size_t ws_size,
                              hipStream_t stream) {
  const float* features = (const float*)d_in[0];
  const int*   captions = (const int*)d_in[1];
  const float* W_proj   = (const float*)d_in[2];
  const float* b_proj   = (const float*)d_in[3];
  const float* embed    = (const float*)d_in[4];
  const float* W_ih     = (const float*)d_in[5];
  const float* W_hh     = (const float*)d_in[6];
  const float* b_ih     = (const float*)d_in[7];
  const float* b_hh     = (const float*)d_in[8];
  const float* W_vocab  = (const float*)d_in[9];
  const float* b_vocab  = (const float*)d_in[10];
  float* out = (float*)d_out;
  char* ws = (char*)d_ws;

  float*          h0      = (float*)(ws + 0x000000);            // 64 KB
  float*          xb      = (float*)(ws + 0x010000);            // 4 MB
  float*          se_part = (float*)(ws + 0x010000);            // 1 MB (reuses xb: dead after k_rnn)
  unsigned short* hsb     = (unsigned short*)(ws + 0x410000);   // 2 MB
  float*          wih_t   = (float*)(ws + 0x610000);            // 64 KB
  unsigned short* wvt     = (unsigned short*)(ws + 0x620000);   // 2.57 MB
  float*          expbv   = (float*)(ws + 0x8A0000);            // 40 KB

  hipLaunchKernelGGL(k_prep, dim3(547), dim3(256), 0, stream,
                     W_vocab, wvt, W_ih, wih_t, b_vocab, expbv, out,
                     features, W_proj, b_proj, h0);
  hipLaunchKernelGGL(k_xb,   dim3(NROW*32/256), dim3(256), 0, stream,
                     captions, embed, wih_t, b_ih, b_hh, xb);
  hipLaunchKernelGGL(k_rnn,  dim3(NB), dim3(256), 0, stream, h0, xb, W_hh, hsb);
  hipLaunchKernelGGL(k_loss, dim3(32*VT), dim3(256), 0, stream, hsb, wvt, expbv, se_part);
  hipLaunchKernelGGL(k_final, dim3(NROW/32), dim3(256), 0, stream,
                     hsb, wvt, b_vocab, se_part, captions, out);
}

// Round 8
// 94.165 us; speedup vs baseline: 3.5155x; 1.1827x over previous
//
#include <hip/hip_runtime.h>
#include <hip/hip_bf16.h>
#include <math.h>

typedef __attribute__((ext_vector_type(8))) short short8;
typedef __attribute__((ext_vector_type(4))) float f32x4;
typedef __attribute__((ext_vector_type(4))) unsigned int u32x4;

#define NB   128   // batch
#define TT   64    // timesteps (T-1)
#define DD   512   // feature dim
#define HH   128   // hidden dim
#define WVD  128   // wordvec dim
#define VV   10000 // vocab
#define VP   10048 // vocab padded to multiple of 64
#define NROW (NB*TT)
#define NTILE (VP/64)    // 157 column tiles of 64
#define VT   32          // col-tile streams (blocks per row-block)
#define TILE_BYTES 16384 // 64 cols x 128 k x 2 B
#define LOG2E 1.44269504088896f
#define LN2   0.69314718055995f

__device__ __forceinline__ unsigned short f2bf(float x) {
  union { float f; unsigned int u; } v; v.f = x;
  unsigned int r = v.u + 0x7fffu + ((v.u >> 16) & 1u);
  return (unsigned short)(r >> 16);
}
__device__ __forceinline__ float bf2f(unsigned short u) {
  union { unsigned int i; float f; } v; v.i = ((unsigned int)u) << 16; return v.f;
}
__device__ __forceinline__ short8 cvt2bf8(f32x4 a, f32x4 b) {
  short8 t;
  t[0]=(short)f2bf(a[0]); t[1]=(short)f2bf(a[1]);
  t[2]=(short)f2bf(a[2]); t[3]=(short)f2bf(a[3]);
  t[4]=(short)f2bf(b[0]); t[5]=(short)f2bf(b[1]);
  t[6]=(short)f2bf(b[2]); t[7]=(short)f2bf(b[3]);
  return t;
}

// ---------------------------------------------------------------------------
// K_main: one fused launch.
//   b in [0,128)   : full RNN pipeline for sample n=b:
//                    h0 (VALU GEMV) + embed gather->bf16 + xb via MFMA + the
//                    64-step recurrence, all in LDS/regs; writes hsb only.
//   b in [128,442) : Wvt[v][k] = bf16(W_vocab[k][v]) (64x64 tile transpose)
//   b in [442,482) : expbv[v] = exp(b_vocab[v]) (0 for pad)
//   b == 482       : out = 0
// LDS layout (RNN branch), 99328 B total:
//   xl    [64][128] f32  @ 0      (32 KB)   xb results
//   hl    [64][128] bf16 @ 32768  (16 KB)   h history (log2e-scaled)
//                                           (prologue reuses as fl/red scratch)
//   xbf   [64][128] bf16 @ 49152  (16 KB)   x, XOR-swizzled rows
//   wihbf [128][128]bf16 @ 65536  (32 KB)   W_ih, XOR-swizzled rows
//   hbuf  [2][128] f32   @ 98304  (1 KB)    double-buffered h
// ---------------------------------------------------------------------------
__global__ __launch_bounds__(256) void k_main(
    const float* __restrict__ Wv, unsigned short* __restrict__ Wvt,
    const float* __restrict__ bv, float* __restrict__ expbv,
    float* __restrict__ out,
    const float* __restrict__ features, const float* __restrict__ Wp,
    const float* __restrict__ bp,
    const int* __restrict__ captions, const float* __restrict__ embed,
    const float* __restrict__ Wih, const float* __restrict__ bih,
    const float* __restrict__ bhh, const float* __restrict__ Whh,
    unsigned short* __restrict__ hsb) {
  __shared__ __align__(16) char smem[99328];
  int b = blockIdx.x, tid = threadIdx.x;

  if (b >= 128) {
    if (b < 442) {
      // ---- W_vocab transpose tile ----
      float (*tile)[65] = (float (*)[65])smem;
      int tb = b - 128;
      int bvv = (tb >> 1) * 64;
      int bk  = (tb & 1) * 64;
      int tv = tid & 63;
      int tk0 = tid >> 6;
      #pragma unroll
      for (int kk = 0; kk < 64; kk += 4) {
        int k = bk + kk + tk0;
        int v = bvv + tv;
        tile[kk + tk0][tv] = (v < VV) ? Wv[(size_t)k*VV + v] : 0.f;
      }
      __syncthreads();
      int tk = tid & 63;
      int tv0 = tid >> 6;
      #pragma unroll
      for (int vv = 0; vv < 64; vv += 4) {
        int v = bvv + vv + tv0;
        Wvt[(size_t)v*HH + bk + tk] = f2bf(tile[tk][vv + tv0]);
      }
    } else if (b < 482) {
      int v = (b - 442)*256 + tid;
      if (v < VP) expbv[v] = (v < VV) ? __expf(bv[v]) : 0.f;
    } else {
      if (tid == 0) out[0] = 0.f;
    }
    return;
  }

  // ======================= RNN branch, sample n = b =======================
  int n = b;
  float* xl            = (float*)smem;                    // [64*128]
  unsigned short* hl   = (unsigned short*)(smem + 32768); // [64*128]
  char* xbf            = smem + 49152;
  char* wihbf          = smem + 65536;
  float* hbuf          = (float*)(smem + 98304);          // [2*128]
  int w = tid >> 6, l = tid & 63;
  int l4 = l >> 4, lc = l & 15;

  // ---- phase 0: h0 = features[n] @ W_proj + b_proj  (into hbuf[0]) ----
  {
    float* fl  = (float*)(smem + 32768);         // 512 f (hl scratch)
    f32x4* red = (f32x4*)(smem + 32768 + 2048);  // 256 f32x4
    fl[tid]       = features[n*DD + tid];
    fl[tid + 256] = features[n*DD + 256 + tid];
    __syncthreads();
    int jq = (tid & 31) * 4;
    int ks = tid >> 5;
    f32x4 acc = {0.f,0.f,0.f,0.f};
    const float* wp = Wp + (size_t)(ks*64)*HH + jq;
    #pragma unroll 4
    for (int k = 0; k < 64; ++k) {
      f32x4 wv = *(const f32x4*)(wp + (size_t)k*HH);
      acc += fl[ks*64 + k] * wv;
    }
    red[ks*32 + (tid & 31)] = acc;
    __syncthreads();
    if (tid < 32) {
      f32x4 s = red[tid];
      #pragma unroll
      for (int i = 1; i < 8; ++i) s += red[i*32 + tid];
      s += *(const f32x4*)(bp + tid*4);
      *(f32x4*)(hbuf + tid*4) = s;
    }
  }

  // ---- phase 1: stage W_ih and x (embed gather) as swizzled bf16 ----
  {
    // W_ih: row = tid>>1 (0..127), half = tid&1 (64 floats)
    int row = tid >> 1, half = tid & 1;
    const float* src = Wih + (size_t)row*WVD + half*64;
    #pragma unroll
    for (int i = 0; i < 8; ++i) {
      f32x4 a = *(const f32x4*)(src + i*8);
      f32x4 c = *(const f32x4*)(src + i*8 + 4);
      int chunk = half*8 + i;
      *(short8*)(wihbf + row*256 + ((chunk << 4) ^ ((row & 7) << 4))) = cvt2bf8(a, c);
    }
    // x: row(t) = tid>>2 (0..63), seg = tid&3 (32 floats)
    int rt = tid >> 2, seg = tid & 3;
    int token = captions[n*65 + rt];
    const float* xs = embed + (size_t)token*WVD + seg*32;
    #pragma unroll
    for (int i = 0; i < 4; ++i) {
      f32x4 a = *(const f32x4*)(xs + i*8);
      f32x4 c = *(const f32x4*)(xs + i*8 + 4);
      int chunk = seg*4 + i;
      *(short8*)(xbf + rt*256 + ((chunk << 4) ^ ((rt & 7) << 4))) = cvt2bf8(a, c);
    }
  }
  // W_hh row-half into registers (issue early; latency hides under MFMA)
  int j = w*32 + (l & 31);
  int kb = (l >> 5) * 64;
  float wr_[64];
  const float* wsrc = Whh + (size_t)j*HH + kb;
  #pragma unroll
  for (int i = 0; i < 16; ++i) {
    f32x4 v = *(const f32x4*)(wsrc + i*4);
    wr_[i*4+0]=v[0]; wr_[i*4+1]=v[1]; wr_[i*4+2]=v[2]; wr_[i*4+3]=v[3];
  }
  __syncthreads();

  // ---- phase 2: xb = x @ W_ih^T via MFMA -> xl (+biases) ----
  {
    short8 axf[4];
    int rowa = w*16 + lc;
    #pragma unroll
    for (int ks = 0; ks < 4; ++ks)
      axf[ks] = *(const short8*)(xbf + rowa*256 + (((ks*4 + l4) << 4) ^ ((rowa & 7) << 4)));
    #pragma unroll
    for (int ct = 0; ct < 8; ++ct) {
      int rowb = ct*16 + lc;
      f32x4 acc = {0.f,0.f,0.f,0.f};
      #pragma unroll
      for (int ks = 0; ks < 4; ++ks) {
        short8 bf = *(const short8*)(wihbf + rowb*256 + (((ks*4 + l4) << 4) ^ ((rowb & 7) << 4)));
        acc = __builtin_amdgcn_mfma_f32_16x16x32_bf16(axf[ks], bf, acc, 0, 0, 0);
      }
      int col = ct*16 + lc;
      float bb = bih[col] + bhh[col];
      #pragma unroll
      for (int jj = 0; jj < 4; ++jj)
        xl[(w*16 + l4*4 + jj)*HH + col] = acc[jj] + bb;
    }
  }
  __syncthreads();

  // ---- phase 3: 64-step recurrence (LDS+VALU only) ----
  int cur = 0;
  for (int t = 0; t < TT; ++t) {
    float s0=0.f, s1=0.f, s2=0.f, s3=0.f;
    const float* hr = hbuf + cur*HH + kb;
    #pragma unroll
    for (int i = 0; i < 16; ++i) {
      f32x4 hv = *(const f32x4*)(hr + i*4);   // 2-addr broadcast, conflict-free
      s0 += hv[0]*wr_[i*4+0]; s1 += hv[1]*wr_[i*4+1];
      s2 += hv[2]*wr_[i*4+2]; s3 += hv[3]*wr_[i*4+3];
    }
    float s = (s0+s1)+(s2+s3);
    s += __shfl_xor(s, 32);                   // combine the two K-halves
    float v = s + xl[t*HH + j];
    float e = __builtin_amdgcn_exp2f(v * (2.0f*LOG2E));
    float h = 1.0f - 2.0f*__builtin_amdgcn_rcpf(e + 1.0f);  // tanh
    if (l < 32) {
      hbuf[(cur^1)*HH + j] = h;
      hl[t*HH + j] = f2bf(h * LOG2E);
    }
    __syncthreads();
    cur ^= 1;
  }
  // flush h history -> global (coalesced 16B)
  unsigned short* dst = hsb + (size_t)n*TT*HH;
  #pragma unroll
  for (int it = 0; it < 4; ++it) {
    int o = it*256 + tid;
    *(u32x4*)(dst + o*8) = *(const u32x4*)(hl + o*8);
  }
}

// ---------------------------------------------------------------------------
// K_loss: sum-exp of scores via LDS-staged B, 2-phase pipeline.
// Grid = rb(32 row-blocks) x vt(32 col streams), blockIdx = rb*32+vt so all
// 32 blocks sharing a tile stream land on one XCD (wgid%8 = vt%8).
// Tile = 64 cols (16 KB bf16), double-buffered via global_load_lds width=16.
// XOR-swizzle on the pre-swizzled GLOBAL source (linear LDS dest) and on the
// ds_read address -> conflict-free b128 reads (verified: 0 bank conflicts).
// Output: per-(vt,row) partial sums, NO atomics.
// ---------------------------------------------------------------------------
__global__ __launch_bounds__(256) void k_loss(
    const unsigned short* __restrict__ hsb,
    const unsigned short* __restrict__ wvt,
    const float* __restrict__ expbv,
    float* __restrict__ se_part) {
  __shared__ unsigned short bt[2][TILE_BYTES/2];   // 2 x 16 KB
  int tid = threadIdx.x;
  int w = tid >> 6, l = tid & 63;
  int l4 = l >> 4, lc = l & 15;
  int rb = blockIdx.x >> 5;
  int vt = blockIdx.x & 31;
  int wrow = rb*256 + w*64;

  short8 af[4][4];
  #pragma unroll
  for (int sm = 0; sm < 4; ++sm)
    #pragma unroll
    for (int ks = 0; ks < 4; ++ks)
      af[sm][ks] = *(const short8*)(hsb + (size_t)(wrow + sm*16 + lc)*HH + ks*32 + l4*8);

  int T = (lc & 7) << 4;
  int sb[4];
  #pragma unroll
  for (int ks = 0; ks < 4; ++ks) sb[ks] = ((ks*64) + l4*16) ^ T;

#define STAGE(bufi, ct) do {                                                  \
    const char* _gb = (const char*)wvt + (size_t)(ct)*TILE_BYTES;             \
    _Pragma("unroll")                                                         \
    for (int q = 0; q < 4; ++q) {                                             \
      int _off = w*4096 + q*1024 + l*16;                                      \
      int _src = _off ^ (((_off >> 8) & 7) << 4);                             \
      __builtin_amdgcn_global_load_lds(                                       \
        (const __attribute__((address_space(1))) void*)(_gb + _src),          \
        (__attribute__((address_space(3))) void*)((char*)&bt[bufi][0] + w*4096 + q*1024), \
        16, 0, 0);                                                            \
    }                                                                         \
  } while (0)

#define EBLOAD(dst, ct) do {                                                  \
    const float* _e = expbv + (ct)*64 + lc;                                   \
    dst[0] = _e[0]; dst[1] = _e[16]; dst[2] = _e[32]; dst[3] = _e[48];        \
  } while (0)

#define COMPUTE(bufi, ebv_) do {                                              \
    const char* _Bb = (const char*)&bt[bufi][0];                              \
    _Pragma("unroll")                                                         \
    for (int st = 0; st < 4; ++st) {                                          \
      const char* _Bs = _Bb + st*4096 + lc*256;                               \
      short8 _b0 = *(const short8*)(_Bs + sb[0]);                             \
      short8 _b1 = *(const short8*)(_Bs + sb[1]);                             \
      short8 _b2 = *(const short8*)(_Bs + sb[2]);                             \
      short8 _b3 = *(const short8*)(_Bs + sb[3]);                             \
      float _eb = ebv_[st];                                                   \
      _Pragma("unroll")                                                       \
      for (int sm = 0; sm < 4; ++sm) {                                        \
        f32x4 _acc = {0.f,0.f,0.f,0.f};                                       \
        _acc = __builtin_amdgcn_mfma_f32_16x16x32_bf16(af[sm][0], _b0, _acc, 0,0,0); \
        _acc = __builtin_amdgcn_mfma_f32_16x16x32_bf16(af[sm][1], _b1, _acc, 0,0,0); \
        _acc = __builtin_amdgcn_mfma_f32_16x16x32_bf16(af[sm][2], _b2, _acc, 0,0,0); \
        _acc = __builtin_amdgcn_mfma_f32_16x16x32_bf16(af[sm][3], _b3, _acc, 0,0,0); \
        _Pragma("unroll")                                                     \
        for (int jj = 0; jj < 4; ++jj)                                        \
          se[sm][jj] = fmaf(__builtin_amdgcn_exp2f(_acc[jj]), _eb, se[sm][jj]); \
      }                                                                       \
    }                                                                         \
  } while (0)

  float se[4][4] = {{0.f}};
  float ebc[4], ebn[4];
  STAGE(0, vt);
  EBLOAD(ebc, vt);
  __syncthreads();
  int i = 0;
  for (;;) {
    int nextct = vt + (i+1)*VT;
    if (nextct < NTILE) { STAGE((i+1)&1, nextct); EBLOAD(ebn, nextct); }
    COMPUTE(i&1, ebc);
    if (nextct >= NTILE) break;
    __syncthreads();
    ebc[0]=ebn[0]; ebc[1]=ebn[1]; ebc[2]=ebn[2]; ebc[3]=ebn[3];
    ++i;
  }

  #pragma unroll
  for (int sm = 0; sm < 4; ++sm)
    #pragma unroll
    for (int jj = 0; jj < 4; ++jj) {
      float v = se[sm][jj];
      v += __shfl_xor(v, 1); v += __shfl_xor(v, 2);
      v += __shfl_xor(v, 4); v += __shfl_xor(v, 8);
      se[sm][jj] = v;
    }
  if (lc == 0) {
    #pragma unroll
    for (int sm = 0; sm < 4; ++sm)
      #pragma unroll
      for (int jj = 0; jj < 4; ++jj)
        se_part[(size_t)vt*NROW + wrow + sm*16 + l4*4 + jj] = se[sm][jj];
  }
#undef STAGE
#undef EBLOAD
#undef COMPUTE
}

// ---------------------------------------------------------------------------
// K_final: sum 32 partials per row + target score + masked NLL reduction.
// ---------------------------------------------------------------------------
__global__ __launch_bounds__(256) void k_final(
    const unsigned short* __restrict__ hsb,
    const unsigned short* __restrict__ wvt,
    const float* __restrict__ bv,
    const float* __restrict__ se_part,
    const int* __restrict__ captions,
    float* __restrict__ out) {
  int tid = threadIdx.x;
  int w = tid >> 6, l = tid & 63;
  int row = blockIdx.x*32 + w*8 + (l >> 3);
  int seg = l & 7;
  int n = row >> 6, t = row & 63;
  int tg = captions[n*65 + t + 1];
  float sep = 0.f;
  #pragma unroll
  for (int i = 0; i < 4; ++i)
    sep += se_part[(size_t)(seg*4 + i)*NROW + row];
  float part = 0.f;
  if (tg != 0) {
    const unsigned short* a = hsb + (size_t)row*HH + seg*16;
    const unsigned short* bq = wvt + (size_t)tg*HH + seg*16;
    short8 a0 = *(const short8*)a, a1 = *(const short8*)(a+8);
    short8 b0 = *(const short8*)bq, b1 = *(const short8*)(bq+8);
    #pragma unroll
    for (int i = 0; i < 8; ++i) {
      part += bf2f((unsigned short)a0[i]) * bf2f((unsigned short)b0[i]);
      part += bf2f((unsigned short)a1[i]) * bf2f((unsigned short)b1[i]);
    }
  }
  part += __shfl_xor(part, 1); sep += __shfl_xor(sep, 1);
  part += __shfl_xor(part, 2); sep += __shfl_xor(sep, 2);
  part += __shfl_xor(part, 4); sep += __shfl_xor(sep, 4);
  if (seg == 0 && tg != 0) {
    float score = part * LN2 + bv[tg];
    float nll = logf(sep) - score;
    atomicAdd(out, nll * (1.0f/128.0f));
  }
}

extern "C" void kernel_launch(void* const* d_in, const int* in_sizes, int n_in,
                              void* d_out, int out_size, void* d_ws, size_t ws_size,
                              hipStream_t stream) {
  const float* features = (const float*)d_in[0];
  const int*   captions = (const int*)d_in[1];
  const float* W_proj   = (const float*)d_in[2];
  const float* b_proj   = (const float*)d_in[3];
  const float* embed    = (const float*)d_in[4];
  const float* W_ih     = (const float*)d_in[5];
  const float* W_hh     = (const float*)d_in[6];
  const float* b_ih     = (const float*)d_in[7];
  const float* b_hh     = (const float*)d_in[8];
  const float* W_vocab  = (const float*)d_in[9];
  const float* b_vocab  = (const float*)d_in[10];
  float* out = (float*)d_out;
  char* ws = (char*)d_ws;

  float*          se_part = (float*)(ws + 0x010000);            // 1 MB
  unsigned short* hsb     = (unsigned short*)(ws + 0x410000);   // 2 MB
  unsigned short* wvt     = (unsigned short*)(ws + 0x620000);   // 2.57 MB
  float*          expbv   = (float*)(ws + 0x8A0000);            // 40 KB

  hipLaunchKernelGGL(k_main, dim3(483), dim3(256), 0, stream,
                     W_vocab, wvt, b_vocab, expbv, out,
                     features, W_proj, b_proj, captions, embed,
                     W_ih, b_ih, b_hh, W_hh, hsb);
  hipLaunchKernelGGL(k_loss, dim3(32*VT), dim3(256), 0, stream,
                     hsb, wvt, expbv, se_part);
  hipLaunchKernelGGL(k_final, dim3(NROW/32), dim3(256), 0, stream,
                     hsb, wvt, b_vocab, se_part, captions, out);
}